// Round 2
// baseline (3583.874 us; speedup 1.0000x reference)
//
#include <hip/hip_runtime.h>
#include <hip/hip_bf16.h>

// GraphSAGE forward: proj -> [aggr -> gemm] x2 (+cls fused into gemm2)
// N=200000, E=3200000, IN_DIM=165, HID=64. All fp32.
//
// R2 design notes:
//  - aggregation decoupled from matmul: 16-lane groups x float4 -> one
//    global_load_dwordx4 fetches 4 edge rows; unroll x2 = 8 rows in flight.
//  - matmuls use register-resident W (wave-uniform, loaded once per wave,
//    amortized over grid-stride node loop) + wave-uniform row loads
//    (1 transaction, scalarizable) + plain FMAs. No shfl/LDS in inner loop:
//    ds/bpermute broadcast costs 2-5.8 cyc on the per-CU LDS pipe vs
//    0.5 cyc/CU for FMA across 4 SIMDs.
//  - cls fused into gemm2 epilogue (saves 51MB write + 51MB read).

#define NNODES 200000
#define NEDGES 3200000
#define INDIM 165
#define HID 64

#define SCAN_T 256
#define SCAN_I 8
#define SCAN_CHUNK (SCAN_T * SCAN_I)   // 2048

typedef float f4 __attribute__((ext_vector_type(4)));

// ---------------- proj: h = relu(x @ Wp + bp) -----------------------------
// wave per node (grid-stride), lane = output feature, W in 165 VGPRs.
__global__ void proj_kernel(const float* __restrict__ x,
                            const float* __restrict__ Wp,
                            const float* __restrict__ bp,
                            float* __restrict__ h, int n) {
  int lane = threadIdx.x & 63;
  int gwave = (blockIdx.x * blockDim.x + threadIdx.x) >> 6;
  int nwaves = (gridDim.x * blockDim.x) >> 6;
  float wreg[INDIM];
  #pragma unroll
  for (int k = 0; k < INDIM; ++k) wreg[k] = Wp[k * HID + lane];
  float b = bp[lane];
  for (int node = gwave; node < n; node += nwaves) {
    const float* row = x + (size_t)node * INDIM;
    float acc = b;
    #pragma unroll
    for (int k4 = 0; k4 < INDIM / 4; ++k4) {  // 41 x float4 (rows are 4B-aligned)
      f4 xv;
      __builtin_memcpy(&xv, row + k4 * 4, sizeof(f4));
      acc += xv.x * wreg[k4 * 4 + 0];
      acc += xv.y * wreg[k4 * 4 + 1];
      acc += xv.z * wreg[k4 * 4 + 2];
      acc += xv.w * wreg[k4 * 4 + 3];
    }
    acc += row[INDIM - 1] * wreg[INDIM - 1];
    h[(size_t)node * HID + lane] = fmaxf(acc, 0.f);
  }
}

// ---------------- degree histogram ----------------------------------------
__global__ void degree_kernel(const int* __restrict__ dst, int* __restrict__ counts, int e) {
  int i = blockIdx.x * blockDim.x + threadIdx.x;
  if (i < e) atomicAdd(&counts[dst[i]], 1);
}

// ---------------- scan ----------------------------------------------------
__global__ void scan1_kernel(const int* __restrict__ counts, int* __restrict__ row_ptr,
                             int* __restrict__ bsums, int n) {
  __shared__ int lds[SCAN_T];
  int b = blockIdx.x, t = threadIdx.x;
  int base = b * SCAN_CHUNK + t * SCAN_I;
  int v[SCAN_I];
  int s = 0;
  #pragma unroll
  for (int i = 0; i < SCAN_I; ++i) {
    int idx = base + i;
    v[i] = (idx < n) ? counts[idx] : 0;
    s += v[i];
  }
  lds[t] = s;
  __syncthreads();
  for (int off = 1; off < SCAN_T; off <<= 1) {
    int y = (t >= off) ? lds[t - off] : 0;
    __syncthreads();
    lds[t] += y;
    __syncthreads();
  }
  int incl = lds[t];
  int run = incl - s;
  #pragma unroll
  for (int i = 0; i < SCAN_I; ++i) {
    int idx = base + i;
    if (idx < n) row_ptr[idx] = run;
    run += v[i];
  }
  if (t == SCAN_T - 1) bsums[b] = incl;
}

__global__ void scan2_kernel(int* __restrict__ bsums, int nb) {
  __shared__ int lds[SCAN_T];
  int t = threadIdx.x;
  int v = (t < nb) ? bsums[t] : 0;
  lds[t] = v;
  __syncthreads();
  for (int off = 1; off < SCAN_T; off <<= 1) {
    int y = (t >= off) ? lds[t - off] : 0;
    __syncthreads();
    lds[t] += y;
    __syncthreads();
  }
  if (t < nb) bsums[t] = lds[t] - v;
}

__global__ void scan3_kernel(int* __restrict__ row_ptr, const int* __restrict__ bsums,
                             int* __restrict__ cursor, int n, int e) {
  int i = blockIdx.x * blockDim.x + threadIdx.x;
  if (i < n) {
    int v = row_ptr[i] + bsums[i / SCAN_CHUNK];
    row_ptr[i] = v;
    cursor[i] = v;
  }
  if (i == n) row_ptr[n] = e;
}

// ---------------- scatter edges into CSR ----------------------------------
__global__ void scatter_kernel(const int* __restrict__ src, const int* __restrict__ dst,
                               int* __restrict__ cursor, int* __restrict__ csr_src, int e) {
  int i = blockIdx.x * blockDim.x + threadIdx.x;
  if (i < e) {
    int d = dst[i];
    int pos = atomicAdd(&cursor[d], 1);
    csr_src[pos] = src[i];
  }
}

// ---------------- mean aggregation (pull, CSR) ----------------------------
// wave per node; lanes split into 4 groups of 16; group g handles edge p+g
// with a float4 chunk per lane -> one dwordx4 load serves 4 edge rows.
__global__ void aggr_kernel(const float* __restrict__ hin,
                            const int* __restrict__ row_ptr,
                            const int* __restrict__ csr_src,
                            float* __restrict__ aggr, int n) {
  int lane = threadIdx.x & 63;
  int grp = lane >> 4, sub = lane & 15;
  int node = (blockIdx.x * blockDim.x + threadIdx.x) >> 6;
  if (node >= n) return;
  int r0 = row_ptr[node], r1 = row_ptr[node + 1];
  f4 acc0 = {0.f, 0.f, 0.f, 0.f}, acc1 = {0.f, 0.f, 0.f, 0.f};
  int p = r0;
  for (; p + 8 <= r1; p += 8) {
    int i0 = csr_src[p + grp];
    int i1 = csr_src[p + 4 + grp];
    f4 v0 = *((const f4*)(hin + (size_t)i0 * HID) + sub);
    f4 v1 = *((const f4*)(hin + (size_t)i1 * HID) + sub);
    acc0 += v0;
    acc1 += v1;
  }
  if (p + 4 <= r1) {
    int i0 = csr_src[p + grp];
    acc0 += *((const f4*)(hin + (size_t)i0 * HID) + sub);
    p += 4;
  }
  int rem = r1 - p;
  if (grp < rem) {
    int i0 = csr_src[p + grp];
    acc1 += *((const f4*)(hin + (size_t)i0 * HID) + sub);
  }
  acc0 += acc1;
  #pragma unroll
  for (int c = 0; c < 4; ++c) {
    float v = acc0[c];
    v += __shfl_xor(v, 16, 64);
    v += __shfl_xor(v, 32, 64);
    acc0[c] = v;
  }
  int deg = r1 - r0;
  float rdeg = 1.f / (float)(deg > 1 ? deg : 1);
  if (grp == 0) {
    f4 o = acc0 * rdeg;
    *((f4*)(aggr + (size_t)node * HID) + sub) = o;
  }
}

// ---------------- gemm: hout = relu(aggr@Wl + bl + hin@Wr) ---------------
// wave grid-strides nodes; W columns in 128 VGPRs; wave-uniform row loads.
__global__ void gemm_kernel(const float* __restrict__ aggr,
                            const float* __restrict__ hin,
                            const float* __restrict__ Wl, const float* __restrict__ bl,
                            const float* __restrict__ Wr,
                            float* __restrict__ hout, int n) {
  int lane = threadIdx.x & 63;
  int gwave = (blockIdx.x * blockDim.x + threadIdx.x) >> 6;
  int nwaves = (gridDim.x * blockDim.x) >> 6;
  float wl[HID], wr[HID];
  #pragma unroll
  for (int k = 0; k < HID; ++k) wl[k] = Wl[k * HID + lane];
  #pragma unroll
  for (int k = 0; k < HID; ++k) wr[k] = Wr[k * HID + lane];
  float b = bl[lane];
  for (int node = gwave; node < n; node += nwaves) {
    const f4* ar = (const f4*)(aggr + (size_t)node * HID);
    const f4* hr = (const f4*)(hin + (size_t)node * HID);
    float acc = b;
    #pragma unroll
    for (int k4 = 0; k4 < HID / 4; ++k4) {
      f4 a = ar[k4], hh = hr[k4];
      acc += a.x * wl[k4 * 4 + 0] + a.y * wl[k4 * 4 + 1]
           + a.z * wl[k4 * 4 + 2] + a.w * wl[k4 * 4 + 3];
      acc += hh.x * wr[k4 * 4 + 0] + hh.y * wr[k4 * 4 + 1]
           + hh.z * wr[k4 * 4 + 2] + hh.w * wr[k4 * 4 + 3];
    }
    hout[(size_t)node * HID + lane] = fmaxf(acc, 0.f);
  }
}

// ---------------- gemm2 + cls fused ---------------------------------------
__global__ void gemm_cls_kernel(const float* __restrict__ aggr,
                                const float* __restrict__ hin,
                                const float* __restrict__ Wl, const float* __restrict__ bl,
                                const float* __restrict__ Wr,
                                const float* __restrict__ Wc, const float* __restrict__ bc,
                                float* __restrict__ out, int n) {
  int lane = threadIdx.x & 63;
  int gwave = (blockIdx.x * blockDim.x + threadIdx.x) >> 6;
  int nwaves = (gridDim.x * blockDim.x) >> 6;
  float wl[HID], wr[HID];
  #pragma unroll
  for (int k = 0; k < HID; ++k) wl[k] = Wl[k * HID + lane];
  #pragma unroll
  for (int k = 0; k < HID; ++k) wr[k] = Wr[k * HID + lane];
  float b = bl[lane];
  float wc = Wc[lane];
  float bcv = bc[0];
  for (int node = gwave; node < n; node += nwaves) {
    const f4* ar = (const f4*)(aggr + (size_t)node * HID);
    const f4* hr = (const f4*)(hin + (size_t)node * HID);
    float acc = b;
    #pragma unroll
    for (int k4 = 0; k4 < HID / 4; ++k4) {
      f4 a = ar[k4], hh = hr[k4];
      acc += a.x * wl[k4 * 4 + 0] + a.y * wl[k4 * 4 + 1]
           + a.z * wl[k4 * 4 + 2] + a.w * wl[k4 * 4 + 3];
      acc += hh.x * wr[k4 * 4 + 0] + hh.y * wr[k4 * 4 + 1]
           + hh.z * wr[k4 * 4 + 2] + hh.w * wr[k4 * 4 + 3];
    }
    float hv = fmaxf(acc, 0.f);
    float v = hv * wc;
    v += __shfl_down(v, 32, 64);
    v += __shfl_down(v, 16, 64);
    v += __shfl_down(v, 8, 64);
    v += __shfl_down(v, 4, 64);
    v += __shfl_down(v, 2, 64);
    v += __shfl_down(v, 1, 64);
    if (lane == 0) out[node] = v + bcv;
  }
}

extern "C" void kernel_launch(void* const* d_in, const int* in_sizes, int n_in,
                              void* d_out, int out_size, void* d_ws, size_t ws_size,
                              hipStream_t stream) {
  const float* x   = (const float*)d_in[0];
  const int*   ei  = (const int*)d_in[1];
  const float* Wp  = (const float*)d_in[2];
  const float* bp  = (const float*)d_in[3];
  const float* W1l = (const float*)d_in[4];
  const float* b1l = (const float*)d_in[5];
  const float* W1r = (const float*)d_in[6];
  const float* W2l = (const float*)d_in[7];
  const float* b2l = (const float*)d_in[8];
  const float* W2r = (const float*)d_in[9];
  const float* Wc  = (const float*)d_in[10];
  const float* bc  = (const float*)d_in[11];
  float* out = (float*)d_out;

  const int N = NNODES, E = NEDGES;
  const int* src = ei;
  const int* dst = ei + E;

  char* ws = (char*)d_ws;
  float* h       = (float*)(ws + 0);                 // 51,200,000 B
  float* aggr    = (float*)(ws + 51200000);          // 51,200,000 B
  int*   counts  = (int*)  (ws + 102400000);         // 800,000
  int*   row_ptr = (int*)  (ws + 103200000);         // 800,004 (padded)
  int*   cursor  = (int*)  (ws + 104000256);         // 800,000
  int*   csr_src = (int*)  (ws + 104800256);         // 12,800,000
  int*   bsums   = (int*)  (ws + 117600256);         // small

  hipMemsetAsync(counts, 0, (size_t)N * 4, stream);

  // proj (overlaps with CSR build — independent)
  proj_kernel<<<1024, 256, 0, stream>>>(x, Wp, bp, h, N);

  // CSR build
  degree_kernel<<<(E + 255) / 256, 256, 0, stream>>>(dst, counts, E);
  int nb = (N + SCAN_CHUNK - 1) / SCAN_CHUNK;  // 98
  scan1_kernel<<<nb, SCAN_T, 0, stream>>>(counts, row_ptr, bsums, N);
  scan2_kernel<<<1, SCAN_T, 0, stream>>>(bsums, nb);
  scan3_kernel<<<(N + 256) / 256, 256, 0, stream>>>(row_ptr, bsums, cursor, N, E);
  scatter_kernel<<<(E + 255) / 256, 256, 0, stream>>>(src, dst, cursor, csr_src, E);

  // layer 1: aggregate then gemm (gemm writes h in place — element-wise per node)
  aggr_kernel<<<(N + 3) / 4, 256, 0, stream>>>(h, row_ptr, csr_src, aggr, N);
  gemm_kernel<<<1024, 256, 0, stream>>>(aggr, h, W1l, b1l, W1r, h, N);

  // layer 2: aggregate then gemm+cls fused
  aggr_kernel<<<(N + 3) / 4, 256, 0, stream>>>(h, row_ptr, csr_src, aggr, N);
  gemm_cls_kernel<<<1024, 256, 0, stream>>>(aggr, h, W2l, b2l, W2r, Wc, bc, out, N);
}

// Round 3
// 1398.501 us; speedup vs baseline: 2.5627x; 2.5627x over previous
//
#include <hip/hip_runtime.h>
#include <hip/hip_bf16.h>

// GraphSAGE forward: proj -> [aggr -> gemm] x2 (+cls fused into gemm2)
// N=200000, E=3200000, IN_DIM=165, HID=64. All fp32.
//
// R3 design notes (post-mortem R2: 165/128-float per-lane arrays were
// spilled to scratch -> 1.6GB HBM traffic in proj. Never again.):
//  - matmuls: 8 nodes per wave, K-tiles with NAMED scalar w registers
//    (coalesced L1 loads, amortized over 8 nodes), node-row reads through
//    wave-uniform pointers (readfirstlane'd node index) so the compiler
//    emits s_load on the scalar pipe (doesn't compete with VALU/VMEM/LDS).
//  - aggregation: 16-lane groups x float4 -> one dwordx4 serves 4 edges.
//  - cls fused into gemm2 epilogue.

#define NNODES 200000
#define NEDGES 3200000
#define INDIM 165
#define HID 64

#define SCAN_T 256
#define SCAN_I 8
#define SCAN_CHUNK (SCAN_T * SCAN_I)   // 2048

typedef float f4 __attribute__((ext_vector_type(4)));

// ---------------- proj: h = relu(x @ Wp + bp) -----------------------------
// one wave per 8 nodes; lane = output feature.
#define PROJ_M(m) { \
  float x0_ = r##m[k+0], x1_ = r##m[k+1], x2_ = r##m[k+2], x3_ = r##m[k+3]; \
  a##m = fmaf(x0_, w0, a##m); a##m = fmaf(x1_, w1, a##m); \
  a##m = fmaf(x2_, w2, a##m); a##m = fmaf(x3_, w3, a##m); }

__global__ void proj_kernel(const float* __restrict__ x,
                            const float* __restrict__ Wp,
                            const float* __restrict__ bp,
                            float* __restrict__ h, int n) {
  int lane = threadIdx.x & 63;
  int wave = __builtin_amdgcn_readfirstlane((int)((blockIdx.x * blockDim.x + threadIdx.x) >> 6));
  int n0 = wave * 8;
  if (n0 >= n) return;  // N % 8 == 0 -> octets always full
  const float* r0 = x + (size_t)n0 * INDIM;
  const float* r1 = r0 + INDIM;
  const float* r2 = r1 + INDIM;
  const float* r3 = r2 + INDIM;
  const float* r4 = r3 + INDIM;
  const float* r5 = r4 + INDIM;
  const float* r6 = r5 + INDIM;
  const float* r7 = r6 + INDIM;
  float b = bp[lane];
  float a0=b,a1=b,a2=b,a3=b,a4=b,a5=b,a6=b,a7=b;
  for (int k = 0; k < INDIM - 1; k += 4) {  // 164 = 41 tiles of 4
    float w0 = Wp[(k+0)*HID + lane];
    float w1 = Wp[(k+1)*HID + lane];
    float w2 = Wp[(k+2)*HID + lane];
    float w3 = Wp[(k+3)*HID + lane];
    PROJ_M(0) PROJ_M(1) PROJ_M(2) PROJ_M(3)
    PROJ_M(4) PROJ_M(5) PROJ_M(6) PROJ_M(7)
  }
  {  // k = 164 tail
    float w = Wp[(INDIM-1)*HID + lane];
    a0 = fmaf(r0[INDIM-1], w, a0); a1 = fmaf(r1[INDIM-1], w, a1);
    a2 = fmaf(r2[INDIM-1], w, a2); a3 = fmaf(r3[INDIM-1], w, a3);
    a4 = fmaf(r4[INDIM-1], w, a4); a5 = fmaf(r5[INDIM-1], w, a5);
    a6 = fmaf(r6[INDIM-1], w, a6); a7 = fmaf(r7[INDIM-1], w, a7);
  }
  float* ho = h + (size_t)n0 * HID + lane;
  ho[0*HID] = fmaxf(a0, 0.f); ho[1*HID] = fmaxf(a1, 0.f);
  ho[2*HID] = fmaxf(a2, 0.f); ho[3*HID] = fmaxf(a3, 0.f);
  ho[4*HID] = fmaxf(a4, 0.f); ho[5*HID] = fmaxf(a5, 0.f);
  ho[6*HID] = fmaxf(a6, 0.f); ho[7*HID] = fmaxf(a7, 0.f);
}

// ---------------- degree histogram ----------------------------------------
__global__ void degree_kernel(const int* __restrict__ dst, int* __restrict__ counts, int e) {
  int i = blockIdx.x * blockDim.x + threadIdx.x;
  if (i < e) atomicAdd(&counts[dst[i]], 1);
}

// ---------------- scan ----------------------------------------------------
__global__ void scan1_kernel(const int* __restrict__ counts, int* __restrict__ row_ptr,
                             int* __restrict__ bsums, int n) {
  __shared__ int lds[SCAN_T];
  int b = blockIdx.x, t = threadIdx.x;
  int base = b * SCAN_CHUNK + t * SCAN_I;
  int v[SCAN_I];
  int s = 0;
  #pragma unroll
  for (int i = 0; i < SCAN_I; ++i) {
    int idx = base + i;
    v[i] = (idx < n) ? counts[idx] : 0;
    s += v[i];
  }
  lds[t] = s;
  __syncthreads();
  for (int off = 1; off < SCAN_T; off <<= 1) {
    int y = (t >= off) ? lds[t - off] : 0;
    __syncthreads();
    lds[t] += y;
    __syncthreads();
  }
  int incl = lds[t];
  int run = incl - s;
  #pragma unroll
  for (int i = 0; i < SCAN_I; ++i) {
    int idx = base + i;
    if (idx < n) row_ptr[idx] = run;
    run += v[i];
  }
  if (t == SCAN_T - 1) bsums[b] = incl;
}

__global__ void scan2_kernel(int* __restrict__ bsums, int nb) {
  __shared__ int lds[SCAN_T];
  int t = threadIdx.x;
  int v = (t < nb) ? bsums[t] : 0;
  lds[t] = v;
  __syncthreads();
  for (int off = 1; off < SCAN_T; off <<= 1) {
    int y = (t >= off) ? lds[t - off] : 0;
    __syncthreads();
    lds[t] += y;
    __syncthreads();
  }
  if (t < nb) bsums[t] = lds[t] - v;
}

__global__ void scan3_kernel(int* __restrict__ row_ptr, const int* __restrict__ bsums,
                             int* __restrict__ cursor, int n, int e) {
  int i = blockIdx.x * blockDim.x + threadIdx.x;
  if (i < n) {
    int v = row_ptr[i] + bsums[i / SCAN_CHUNK];
    row_ptr[i] = v;
    cursor[i] = v;
  }
  if (i == n) row_ptr[n] = e;
}

// ---------------- scatter edges into CSR ----------------------------------
__global__ void scatter_kernel(const int* __restrict__ src, const int* __restrict__ dst,
                               int* __restrict__ cursor, int* __restrict__ csr_src, int e) {
  int i = blockIdx.x * blockDim.x + threadIdx.x;
  if (i < e) {
    int d = dst[i];
    int pos = atomicAdd(&cursor[d], 1);
    csr_src[pos] = src[i];
  }
}

// ---------------- mean aggregation (pull, CSR) ----------------------------
__global__ void aggr_kernel(const float* __restrict__ hin,
                            const int* __restrict__ row_ptr,
                            const int* __restrict__ csr_src,
                            float* __restrict__ aggr, int n) {
  int lane = threadIdx.x & 63;
  int grp = lane >> 4, sub = lane & 15;
  int node = (blockIdx.x * blockDim.x + threadIdx.x) >> 6;
  if (node >= n) return;
  int r0 = row_ptr[node], r1 = row_ptr[node + 1];
  f4 acc0 = {0.f, 0.f, 0.f, 0.f}, acc1 = {0.f, 0.f, 0.f, 0.f};
  int p = r0;
  for (; p + 8 <= r1; p += 8) {
    int i0 = csr_src[p + grp];
    int i1 = csr_src[p + 4 + grp];
    f4 v0 = *((const f4*)(hin + (size_t)i0 * HID) + sub);
    f4 v1 = *((const f4*)(hin + (size_t)i1 * HID) + sub);
    acc0 += v0;
    acc1 += v1;
  }
  if (p + 4 <= r1) {
    int i0 = csr_src[p + grp];
    acc0 += *((const f4*)(hin + (size_t)i0 * HID) + sub);
    p += 4;
  }
  int rem = r1 - p;
  if (grp < rem) {
    int i0 = csr_src[p + grp];
    acc1 += *((const f4*)(hin + (size_t)i0 * HID) + sub);
  }
  acc0 += acc1;
  #pragma unroll
  for (int c = 0; c < 4; ++c) {
    float v = acc0[c];
    v += __shfl_xor(v, 16, 64);
    v += __shfl_xor(v, 32, 64);
    acc0[c] = v;
  }
  int deg = r1 - r0;
  float rdeg = 1.f / (float)(deg > 1 ? deg : 1);
  if (grp == 0) {
    f4 o = acc0 * rdeg;
    *((f4*)(aggr + (size_t)node * HID) + sub) = o;
  }
}

// ---------------- gemm: hout = relu(aggr@Wl + bl + hin@Wr) ---------------
// one wave per 8 nodes; lane = out feature; named w regs; uniform f4 row loads.
#define GEMM_M(m) { \
  f4 av = ar##m[kt]; f4 hv = hr##m[kt]; \
  a##m = fmaf(av.x, wl0, a##m); a##m = fmaf(av.y, wl1, a##m); \
  a##m = fmaf(av.z, wl2, a##m); a##m = fmaf(av.w, wl3, a##m); \
  a##m = fmaf(hv.x, wr0, a##m); a##m = fmaf(hv.y, wr1, a##m); \
  a##m = fmaf(hv.z, wr2, a##m); a##m = fmaf(hv.w, wr3, a##m); }

#define GEMM_ROWS(aggrp, hinp) \
  const f4* ar0 = (const f4*)(aggrp + (size_t)n0 * HID); \
  const f4* ar1 = ar0 + HID/4; const f4* ar2 = ar1 + HID/4; \
  const f4* ar3 = ar2 + HID/4; const f4* ar4 = ar3 + HID/4; \
  const f4* ar5 = ar4 + HID/4; const f4* ar6 = ar5 + HID/4; \
  const f4* ar7 = ar6 + HID/4; \
  const f4* hr0 = (const f4*)(hinp + (size_t)n0 * HID); \
  const f4* hr1 = hr0 + HID/4; const f4* hr2 = hr1 + HID/4; \
  const f4* hr3 = hr2 + HID/4; const f4* hr4 = hr3 + HID/4; \
  const f4* hr5 = hr4 + HID/4; const f4* hr6 = hr5 + HID/4; \
  const f4* hr7 = hr6 + HID/4;

#define GEMM_KLOOP(Wlp, Wrp) \
  for (int kt = 0; kt < HID/4; ++kt) { \
    int k = kt * 4; \
    float wl0 = Wlp[(k+0)*HID + lane], wl1 = Wlp[(k+1)*HID + lane]; \
    float wl2 = Wlp[(k+2)*HID + lane], wl3 = Wlp[(k+3)*HID + lane]; \
    float wr0 = Wrp[(k+0)*HID + lane], wr1 = Wrp[(k+1)*HID + lane]; \
    float wr2 = Wrp[(k+2)*HID + lane], wr3 = Wrp[(k+3)*HID + lane]; \
    GEMM_M(0) GEMM_M(1) GEMM_M(2) GEMM_M(3) \
    GEMM_M(4) GEMM_M(5) GEMM_M(6) GEMM_M(7) \
  }

__global__ void gemm_kernel(const float* __restrict__ aggr,
                            const float* __restrict__ hin,
                            const float* __restrict__ Wl, const float* __restrict__ bl,
                            const float* __restrict__ Wr,
                            float* __restrict__ hout, int n) {
  int lane = threadIdx.x & 63;
  int wave = __builtin_amdgcn_readfirstlane((int)((blockIdx.x * blockDim.x + threadIdx.x) >> 6));
  int n0 = wave * 8;
  if (n0 >= n) return;
  GEMM_ROWS(aggr, hin)
  float b = bl[lane];
  float a0=b,a1=b,a2=b,a3=b,a4=b,a5=b,a6=b,a7=b;
  GEMM_KLOOP(Wl, Wr)
  float* ho = hout + (size_t)n0 * HID + lane;
  ho[0*HID] = fmaxf(a0, 0.f); ho[1*HID] = fmaxf(a1, 0.f);
  ho[2*HID] = fmaxf(a2, 0.f); ho[3*HID] = fmaxf(a3, 0.f);
  ho[4*HID] = fmaxf(a4, 0.f); ho[5*HID] = fmaxf(a5, 0.f);
  ho[6*HID] = fmaxf(a6, 0.f); ho[7*HID] = fmaxf(a7, 0.f);
}

// ---------------- gemm2 + cls fused ---------------------------------------
#define CLS_RED(m) { \
  float v = fmaxf(a##m, 0.f) * wc; \
  v += __shfl_down(v, 32, 64); v += __shfl_down(v, 16, 64); \
  v += __shfl_down(v, 8, 64);  v += __shfl_down(v, 4, 64); \
  v += __shfl_down(v, 2, 64);  v += __shfl_down(v, 1, 64); \
  if (lane == 0) out[n0 + m] = v + bcv; }

__global__ void gemm_cls_kernel(const float* __restrict__ aggr,
                                const float* __restrict__ hin,
                                const float* __restrict__ Wl, const float* __restrict__ bl,
                                const float* __restrict__ Wr,
                                const float* __restrict__ Wc, const float* __restrict__ bc,
                                float* __restrict__ out, int n) {
  int lane = threadIdx.x & 63;
  int wave = __builtin_amdgcn_readfirstlane((int)((blockIdx.x * blockDim.x + threadIdx.x) >> 6));
  int n0 = wave * 8;
  if (n0 >= n) return;
  GEMM_ROWS(aggr, hin)
  float b = bl[lane];
  float a0=b,a1=b,a2=b,a3=b,a4=b,a5=b,a6=b,a7=b;
  GEMM_KLOOP(Wl, Wr)
  float wc = Wc[lane];
  float bcv = bc[0];
  CLS_RED(0) CLS_RED(1) CLS_RED(2) CLS_RED(3)
  CLS_RED(4) CLS_RED(5) CLS_RED(6) CLS_RED(7)
}

extern "C" void kernel_launch(void* const* d_in, const int* in_sizes, int n_in,
                              void* d_out, int out_size, void* d_ws, size_t ws_size,
                              hipStream_t stream) {
  const float* x   = (const float*)d_in[0];
  const int*   ei  = (const int*)d_in[1];
  const float* Wp  = (const float*)d_in[2];
  const float* bp  = (const float*)d_in[3];
  const float* W1l = (const float*)d_in[4];
  const float* b1l = (const float*)d_in[5];
  const float* W1r = (const float*)d_in[6];
  const float* W2l = (const float*)d_in[7];
  const float* b2l = (const float*)d_in[8];
  const float* W2r = (const float*)d_in[9];
  const float* Wc  = (const float*)d_in[10];
  const float* bc  = (const float*)d_in[11];
  float* out = (float*)d_out;

  const int N = NNODES, E = NEDGES;
  const int* src = ei;
  const int* dst = ei + E;

  char* ws = (char*)d_ws;
  float* h       = (float*)(ws + 0);                 // 51,200,000 B
  float* aggr    = (float*)(ws + 51200000);          // 51,200,000 B
  int*   counts  = (int*)  (ws + 102400000);         // 800,000
  int*   row_ptr = (int*)  (ws + 103200000);         // 800,004 (padded)
  int*   cursor  = (int*)  (ws + 104000256);         // 800,000
  int*   csr_src = (int*)  (ws + 104800256);         // 12,800,000
  int*   bsums   = (int*)  (ws + 117600256);         // small

  hipMemsetAsync(counts, 0, (size_t)N * 4, stream);

  // proj: 25000 node-octets -> 25000 waves -> 6250 blocks
  proj_kernel<<<6250, 256, 0, stream>>>(x, Wp, bp, h, N);

  // CSR build
  degree_kernel<<<(E + 255) / 256, 256, 0, stream>>>(dst, counts, E);
  int nb = (N + SCAN_CHUNK - 1) / SCAN_CHUNK;  // 98
  scan1_kernel<<<nb, SCAN_T, 0, stream>>>(counts, row_ptr, bsums, N);
  scan2_kernel<<<1, SCAN_T, 0, stream>>>(bsums, nb);
  scan3_kernel<<<(N + 256) / 256, 256, 0, stream>>>(row_ptr, bsums, cursor, N, E);
  scatter_kernel<<<(E + 255) / 256, 256, 0, stream>>>(src, dst, cursor, csr_src, E);

  // layer 1 (gemm writes h in place: only aliasing pair is same-node
  // load->store, a true data dependence)
  aggr_kernel<<<(N + 3) / 4, 256, 0, stream>>>(h, row_ptr, csr_src, aggr, N);
  gemm_kernel<<<6250, 256, 0, stream>>>(aggr, h, W1l, b1l, W1r, h, N);

  // layer 2 + cls
  aggr_kernel<<<(N + 3) / 4, 256, 0, stream>>>(h, row_ptr, csr_src, aggr, N);
  gemm_cls_kernel<<<6250, 256, 0, stream>>>(aggr, h, W2l, b2l, W2r, Wc, bc, out, N);
}

// Round 5
// 1134.145 us; speedup vs baseline: 3.1600x; 1.2331x over previous
//
#include <hip/hip_runtime.h>
#include <hip/hip_bf16.h>

// GraphSAGE forward: proj -> [aggr -> gemm] x2 (+cls fused into gemm2)
// N=200000, E=3200000, IN_DIM=165, HID=64. All fp32.
//
// R5 design notes (post-mortem R4: AS_STRIDE=60 < row width 64 -> tile rows
// overlapped -> corruption. Fix without padding: XOR chunk swizzle):
//  - gemm tiles stored at stride 64 (LDS total exactly 64 KiB with Wl+Wr);
//    f4 chunk c of row r lives at slot c ^ ((r>>2)&3). A thread's 4 rows
//    share (r>>2)&3, the 4 row-groups of a wave differ -> per-read the 4
//    b128s land on 4 distinct bank-quads: conflict-free, zero padding.
//  - K-loop reads x-side as f4 k-chunks: 16 b128 per 4 k's per thread vs
//    128 scalar FMAs -> VALU-bound by construction.
//  - proj: 64x64 LDS tile, stride 57 (>=55 chunk width), unchanged from R4.
//  - aggregation: 16-lane groups x float4 -> one dwordx4 serves 4 edges.
//  - cls fused into gemm2 epilogue.

#define NNODES 200000
#define NEDGES 3200000
#define INDIM 165
#define HID 64

#define SCAN_T 256
#define SCAN_I 8
#define SCAN_CHUNK (SCAN_T * SCAN_I)   // 2048

typedef float f4 __attribute__((ext_vector_type(4)));

// ---------------- proj: h = relu(x @ Wp + bp) -----------------------------
// block = 64 nodes x 64 outs; thread = 4 nodes x 4 outs; K chunked 3x55.
#define XS_STRIDE 57   // >= 55; banks rotate by 25 per row -> conflict-free

__global__ __launch_bounds__(256, 2)
void proj_kernel(const float* __restrict__ x,
                 const float* __restrict__ Wp,
                 const float* __restrict__ bp,
                 float* __restrict__ h, int n) {
  __shared__ float w_s[INDIM * HID];        // 42,240 B
  __shared__ float x_s[64 * XS_STRIDE];     // 14,592 B
  int t = threadIdx.x;
  int tx = t & 15;          // out quad
  int ny4 = (t >> 4) * 4;   // first node of quad
  int n0 = blockIdx.x * 64;

  // stage W (full K) as f4, coalesced
  for (int i = t; i < INDIM * HID / 4; i += 256)
    ((f4*)w_s)[i] = ((const f4*)Wp)[i];

  f4 bv = ((const f4*)bp)[tx];
  f4 acc0 = bv, acc1 = bv, acc2 = bv, acc3 = bv;

  for (int kc = 0; kc < 3; ++kc) {
    // stage x chunk [64 nodes][55 k's]
    for (int i = t; i < 64 * 55; i += 256) {
      int row = i / 55, col = i % 55;
      x_s[row * XS_STRIDE + col] = x[(size_t)(n0 + row) * INDIM + kc * 55 + col];
    }
    __syncthreads();
    #pragma unroll 5
    for (int k = 0; k < 55; ++k) {
      f4 wv = *(const f4*)&w_s[(kc * 55 + k) * HID + tx * 4];
      float x0 = x_s[(ny4 + 0) * XS_STRIDE + k];
      float x1 = x_s[(ny4 + 1) * XS_STRIDE + k];
      float x2 = x_s[(ny4 + 2) * XS_STRIDE + k];
      float x3 = x_s[(ny4 + 3) * XS_STRIDE + k];
      acc0 += x0 * wv; acc1 += x1 * wv; acc2 += x2 * wv; acc3 += x3 * wv;
    }
    __syncthreads();
  }
  acc0.x = fmaxf(acc0.x, 0.f); acc0.y = fmaxf(acc0.y, 0.f); acc0.z = fmaxf(acc0.z, 0.f); acc0.w = fmaxf(acc0.w, 0.f);
  acc1.x = fmaxf(acc1.x, 0.f); acc1.y = fmaxf(acc1.y, 0.f); acc1.z = fmaxf(acc1.z, 0.f); acc1.w = fmaxf(acc1.w, 0.f);
  acc2.x = fmaxf(acc2.x, 0.f); acc2.y = fmaxf(acc2.y, 0.f); acc2.z = fmaxf(acc2.z, 0.f); acc2.w = fmaxf(acc2.w, 0.f);
  acc3.x = fmaxf(acc3.x, 0.f); acc3.y = fmaxf(acc3.y, 0.f); acc3.z = fmaxf(acc3.z, 0.f); acc3.w = fmaxf(acc3.w, 0.f);
  *(f4*)&h[(size_t)(n0 + ny4 + 0) * HID + tx * 4] = acc0;
  *(f4*)&h[(size_t)(n0 + ny4 + 1) * HID + tx * 4] = acc1;
  *(f4*)&h[(size_t)(n0 + ny4 + 2) * HID + tx * 4] = acc2;
  *(f4*)&h[(size_t)(n0 + ny4 + 3) * HID + tx * 4] = acc3;
}

// ---------------- degree histogram ----------------------------------------
__global__ void degree_kernel(const int* __restrict__ dst, int* __restrict__ counts, int e) {
  int i = blockIdx.x * blockDim.x + threadIdx.x;
  if (i < e) atomicAdd(&counts[dst[i]], 1);
}

// ---------------- scan ----------------------------------------------------
__global__ void scan1_kernel(const int* __restrict__ counts, int* __restrict__ row_ptr,
                             int* __restrict__ bsums, int n) {
  __shared__ int lds[SCAN_T];
  int b = blockIdx.x, t = threadIdx.x;
  int base = b * SCAN_CHUNK + t * SCAN_I;
  int v[SCAN_I];
  int s = 0;
  #pragma unroll
  for (int i = 0; i < SCAN_I; ++i) {
    int idx = base + i;
    v[i] = (idx < n) ? counts[idx] : 0;
    s += v[i];
  }
  lds[t] = s;
  __syncthreads();
  for (int off = 1; off < SCAN_T; off <<= 1) {
    int y = (t >= off) ? lds[t - off] : 0;
    __syncthreads();
    lds[t] += y;
    __syncthreads();
  }
  int incl = lds[t];
  int run = incl - s;
  #pragma unroll
  for (int i = 0; i < SCAN_I; ++i) {
    int idx = base + i;
    if (idx < n) row_ptr[idx] = run;
    run += v[i];
  }
  if (t == SCAN_T - 1) bsums[b] = incl;
}

__global__ void scan2_kernel(int* __restrict__ bsums, int nb) {
  __shared__ int lds[SCAN_T];
  int t = threadIdx.x;
  int v = (t < nb) ? bsums[t] : 0;
  lds[t] = v;
  __syncthreads();
  for (int off = 1; off < SCAN_T; off <<= 1) {
    int y = (t >= off) ? lds[t - off] : 0;
    __syncthreads();
    lds[t] += y;
    __syncthreads();
  }
  if (t < nb) bsums[t] = lds[t] - v;
}

__global__ void scan3_kernel(int* __restrict__ row_ptr, const int* __restrict__ bsums,
                             int* __restrict__ cursor, int n, int e) {
  int i = blockIdx.x * blockDim.x + threadIdx.x;
  if (i < n) {
    int v = row_ptr[i] + bsums[i / SCAN_CHUNK];
    row_ptr[i] = v;
    cursor[i] = v;
  }
  if (i == n) row_ptr[n] = e;
}

// ---------------- scatter edges into CSR ----------------------------------
__global__ void scatter_kernel(const int* __restrict__ src, const int* __restrict__ dst,
                               int* __restrict__ cursor, int* __restrict__ csr_src, int e) {
  int i = blockIdx.x * blockDim.x + threadIdx.x;
  if (i < e) {
    int d = dst[i];
    int pos = atomicAdd(&cursor[d], 1);
    csr_src[pos] = src[i];
  }
}

// ---------------- mean aggregation (pull, CSR) ----------------------------
__global__ void aggr_kernel(const float* __restrict__ hin,
                            const int* __restrict__ row_ptr,
                            const int* __restrict__ csr_src,
                            float* __restrict__ aggr, int n) {
  int lane = threadIdx.x & 63;
  int grp = lane >> 4, sub = lane & 15;
  int node = (blockIdx.x * blockDim.x + threadIdx.x) >> 6;
  if (node >= n) return;
  int r0 = row_ptr[node], r1 = row_ptr[node + 1];
  f4 acc0 = {0.f, 0.f, 0.f, 0.f}, acc1 = {0.f, 0.f, 0.f, 0.f};
  int p = r0;
  for (; p + 8 <= r1; p += 8) {
    int i0 = csr_src[p + grp];
    int i1 = csr_src[p + 4 + grp];
    f4 v0 = *((const f4*)(hin + (size_t)i0 * HID) + sub);
    f4 v1 = *((const f4*)(hin + (size_t)i1 * HID) + sub);
    acc0 += v0;
    acc1 += v1;
  }
  if (p + 4 <= r1) {
    int i0 = csr_src[p + grp];
    acc0 += *((const f4*)(hin + (size_t)i0 * HID) + sub);
    p += 4;
  }
  int rem = r1 - p;
  if (grp < rem) {
    int i0 = csr_src[p + grp];
    acc1 += *((const f4*)(hin + (size_t)i0 * HID) + sub);
  }
  acc0 += acc1;
  #pragma unroll
  for (int c = 0; c < 4; ++c) {
    float v = acc0[c];
    v += __shfl_xor(v, 16, 64);
    v += __shfl_xor(v, 32, 64);
    acc0[c] = v;
  }
  int deg = r1 - r0;
  float rdeg = 1.f / (float)(deg > 1 ? deg : 1);
  if (grp == 0) {
    f4 o = acc0 * rdeg;
    *((f4*)(aggr + (size_t)node * HID) + sub) = o;
  }
}

// ---------------- gemm: hout = relu(aggr@Wl + bl + hin@Wr) ---------------
// block = 64 nodes x 64 outs; thread = 4 nodes x 4 outs. LDS exactly 64 KiB:
// Wl + Wr + swizzled a/h tiles (stride 64, chunk c of row r at c^((r>>2)&3)).
// In-place hout==hin safe: rows staged to LDS + barrier before stores.

#define GEMM_STAGE(aggrp, hinp) \
  for (int i = t; i < HID * HID / 4; i += 256) { \
    ((f4*)wl_s)[i] = ((const f4*)Wl)[i]; \
    ((f4*)wr_s)[i] = ((const f4*)Wr)[i]; \
  } \
  for (int i = t; i < 64 * 16; i += 256) { \
    int row = i >> 4, c4 = i & 15; \
    int cs = c4 ^ ((row >> 2) & 3); \
    ((f4*)a_s)[row * 16 + cs] = ((const f4*)(aggrp + (size_t)(n0 + row) * HID))[c4]; \
    ((f4*)h_s)[row * 16 + cs] = ((const f4*)(hinp + (size_t)(n0 + row) * HID))[c4]; \
  } \
  __syncthreads();

#define GEMM_KLOOP() \
  _Pragma("unroll 4") \
  for (int kc = 0; kc < 16; ++kc) { \
    int k = kc * 4; \
    f4 wl0 = *(const f4*)&wl_s[(k+0) * HID + tx * 4]; \
    f4 wl1 = *(const f4*)&wl_s[(k+1) * HID + tx * 4]; \
    f4 wl2 = *(const f4*)&wl_s[(k+2) * HID + tx * 4]; \
    f4 wl3 = *(const f4*)&wl_s[(k+3) * HID + tx * 4]; \
    f4 wr0 = *(const f4*)&wr_s[(k+0) * HID + tx * 4]; \
    f4 wr1 = *(const f4*)&wr_s[(k+1) * HID + tx * 4]; \
    f4 wr2 = *(const f4*)&wr_s[(k+2) * HID + tx * 4]; \
    f4 wr3 = *(const f4*)&wr_s[(k+3) * HID + tx * 4]; \
    int cs = kc ^ q3; \
    f4 av0 = ((const f4*)a_s)[(ny4 + 0) * 16 + cs]; \
    f4 av1 = ((const f4*)a_s)[(ny4 + 1) * 16 + cs]; \
    f4 av2 = ((const f4*)a_s)[(ny4 + 2) * 16 + cs]; \
    f4 av3 = ((const f4*)a_s)[(ny4 + 3) * 16 + cs]; \
    f4 hv0 = ((const f4*)h_s)[(ny4 + 0) * 16 + cs]; \
    f4 hv1 = ((const f4*)h_s)[(ny4 + 1) * 16 + cs]; \
    f4 hv2 = ((const f4*)h_s)[(ny4 + 2) * 16 + cs]; \
    f4 hv3 = ((const f4*)h_s)[(ny4 + 3) * 16 + cs]; \
    acc0 += av0.x * wl0 + av0.y * wl1 + av0.z * wl2 + av0.w * wl3 \
          + hv0.x * wr0 + hv0.y * wr1 + hv0.z * wr2 + hv0.w * wr3; \
    acc1 += av1.x * wl0 + av1.y * wl1 + av1.z * wl2 + av1.w * wl3 \
          + hv1.x * wr0 + hv1.y * wr1 + hv1.z * wr2 + hv1.w * wr3; \
    acc2 += av2.x * wl0 + av2.y * wl1 + av2.z * wl2 + av2.w * wl3 \
          + hv2.x * wr0 + hv2.y * wr1 + hv2.z * wr2 + hv2.w * wr3; \
    acc3 += av3.x * wl0 + av3.y * wl1 + av3.z * wl2 + av3.w * wl3 \
          + hv3.x * wr0 + hv3.y * wr1 + hv3.z * wr2 + hv3.w * wr3; \
  }

__global__ __launch_bounds__(256, 2)
void gemm_kernel(const float* __restrict__ aggr,
                 const float* hin,
                 const float* __restrict__ Wl, const float* __restrict__ bl,
                 const float* __restrict__ Wr,
                 float* hout, int n) {
  __shared__ float wl_s[HID * HID];   // 16,384 B
  __shared__ float wr_s[HID * HID];   // 16,384 B
  __shared__ float a_s[64 * 64];      // 16,384 B
  __shared__ float h_s[64 * 64];      // 16,384 B  -> total 65,536 B
  int t = threadIdx.x;
  int tx = t & 15;
  int ny4 = (t >> 4) * 4;
  int q3 = (t >> 4) & 3;
  int n0 = blockIdx.x * 64;

  GEMM_STAGE(aggr, hin)

  f4 bv = ((const f4*)bl)[tx];
  f4 acc0 = bv, acc1 = bv, acc2 = bv, acc3 = bv;
  GEMM_KLOOP()

  acc0.x = fmaxf(acc0.x, 0.f); acc0.y = fmaxf(acc0.y, 0.f); acc0.z = fmaxf(acc0.z, 0.f); acc0.w = fmaxf(acc0.w, 0.f);
  acc1.x = fmaxf(acc1.x, 0.f); acc1.y = fmaxf(acc1.y, 0.f); acc1.z = fmaxf(acc1.z, 0.f); acc1.w = fmaxf(acc1.w, 0.f);
  acc2.x = fmaxf(acc2.x, 0.f); acc2.y = fmaxf(acc2.y, 0.f); acc2.z = fmaxf(acc2.z, 0.f); acc2.w = fmaxf(acc2.w, 0.f);
  acc3.x = fmaxf(acc3.x, 0.f); acc3.y = fmaxf(acc3.y, 0.f); acc3.z = fmaxf(acc3.z, 0.f); acc3.w = fmaxf(acc3.w, 0.f);
  *(f4*)&hout[(size_t)(n0 + ny4 + 0) * HID + tx * 4] = acc0;
  *(f4*)&hout[(size_t)(n0 + ny4 + 1) * HID + tx * 4] = acc1;
  *(f4*)&hout[(size_t)(n0 + ny4 + 2) * HID + tx * 4] = acc2;
  *(f4*)&hout[(size_t)(n0 + ny4 + 3) * HID + tx * 4] = acc3;
}

// ---------------- gemm2 + cls fused ---------------------------------------
__global__ __launch_bounds__(256, 2)
void gemm_cls_kernel(const float* __restrict__ aggr,
                     const float* __restrict__ hin,
                     const float* __restrict__ Wl, const float* __restrict__ bl,
                     const float* __restrict__ Wr,
                     const float* __restrict__ Wc, const float* __restrict__ bc,
                     float* __restrict__ out, int n) {
  __shared__ float wl_s[HID * HID];
  __shared__ float wr_s[HID * HID];
  __shared__ float a_s[64 * 64];
  __shared__ float h_s[64 * 64];
  int t = threadIdx.x;
  int tx = t & 15;
  int ny4 = (t >> 4) * 4;
  int q3 = (t >> 4) & 3;
  int n0 = blockIdx.x * 64;

  GEMM_STAGE(aggr, hin)

  f4 bv = ((const f4*)bl)[tx];
  f4 acc0 = bv, acc1 = bv, acc2 = bv, acc3 = bv;
  GEMM_KLOOP()

  f4 wcv = ((const f4*)Wc)[tx];
  float bcv = bc[0];
  float s0 = fmaxf(acc0.x,0.f)*wcv.x + fmaxf(acc0.y,0.f)*wcv.y + fmaxf(acc0.z,0.f)*wcv.z + fmaxf(acc0.w,0.f)*wcv.w;
  float s1 = fmaxf(acc1.x,0.f)*wcv.x + fmaxf(acc1.y,0.f)*wcv.y + fmaxf(acc1.z,0.f)*wcv.z + fmaxf(acc1.w,0.f)*wcv.w;
  float s2 = fmaxf(acc2.x,0.f)*wcv.x + fmaxf(acc2.y,0.f)*wcv.y + fmaxf(acc2.z,0.f)*wcv.z + fmaxf(acc2.w,0.f)*wcv.w;
  float s3 = fmaxf(acc3.x,0.f)*wcv.x + fmaxf(acc3.y,0.f)*wcv.y + fmaxf(acc3.z,0.f)*wcv.z + fmaxf(acc3.w,0.f)*wcv.w;
  #pragma unroll
  for (int off = 1; off < 16; off <<= 1) {
    s0 += __shfl_xor(s0, off, 64);
    s1 += __shfl_xor(s1, off, 64);
    s2 += __shfl_xor(s2, off, 64);
    s3 += __shfl_xor(s3, off, 64);
  }
  if (tx == 0) {
    out[n0 + ny4 + 0] = s0 + bcv;
    out[n0 + ny4 + 1] = s1 + bcv;
    out[n0 + ny4 + 2] = s2 + bcv;
    out[n0 + ny4 + 3] = s3 + bcv;
  }
}

extern "C" void kernel_launch(void* const* d_in, const int* in_sizes, int n_in,
                              void* d_out, int out_size, void* d_ws, size_t ws_size,
                              hipStream_t stream) {
  const float* x   = (const float*)d_in[0];
  const int*   ei  = (const int*)d_in[1];
  const float* Wp  = (const float*)d_in[2];
  const float* bp  = (const float*)d_in[3];
  const float* W1l = (const float*)d_in[4];
  const float* b1l = (const float*)d_in[5];
  const float* W1r = (const float*)d_in[6];
  const float* W2l = (const float*)d_in[7];
  const float* b2l = (const float*)d_in[8];
  const float* W2r = (const float*)d_in[9];
  const float* Wc  = (const float*)d_in[10];
  const float* bc  = (const float*)d_in[11];
  float* out = (float*)d_out;

  const int N = NNODES, E = NEDGES;
  const int* src = ei;
  const int* dst = ei + E;

  char* ws = (char*)d_ws;
  float* h       = (float*)(ws + 0);                 // 51,200,000 B
  float* aggr    = (float*)(ws + 51200000);          // 51,200,000 B
  int*   counts  = (int*)  (ws + 102400000);         // 800,000
  int*   row_ptr = (int*)  (ws + 103200000);         // 800,004 (padded)
  int*   cursor  = (int*)  (ws + 104000256);         // 800,000
  int*   csr_src = (int*)  (ws + 104800256);         // 12,800,000
  int*   bsums   = (int*)  (ws + 117600256);         // small

  hipMemsetAsync(counts, 0, (size_t)N * 4, stream);

  // proj: 200000/64 = 3125 blocks
  proj_kernel<<<3125, 256, 0, stream>>>(x, Wp, bp, h, N);

  // CSR build
  degree_kernel<<<(E + 255) / 256, 256, 0, stream>>>(dst, counts, E);
  int nb = (N + SCAN_CHUNK - 1) / SCAN_CHUNK;  // 98
  scan1_kernel<<<nb, SCAN_T, 0, stream>>>(counts, row_ptr, bsums, N);
  scan2_kernel<<<1, SCAN_T, 0, stream>>>(bsums, nb);
  scan3_kernel<<<(N + 256) / 256, 256, 0, stream>>>(row_ptr, bsums, cursor, N, E);
  scatter_kernel<<<(E + 255) / 256, 256, 0, stream>>>(src, dst, cursor, csr_src, E);

  // layer 1
  aggr_kernel<<<(N + 3) / 4, 256, 0, stream>>>(h, row_ptr, csr_src, aggr, N);
  gemm_kernel<<<3125, 256, 0, stream>>>(aggr, h, W1l, b1l, W1r, h, N);

  // layer 2 + cls
  aggr_kernel<<<(N + 3) / 4, 256, 0, stream>>>(h, row_ptr, csr_src, aggr, N);
  gemm_cls_kernel<<<3125, 256, 0, stream>>>(aggr, h, W2l, b2l, W2r, Wc, bc, out, N);
}

// Round 6
// 1039.788 us; speedup vs baseline: 3.4467x; 1.0907x over previous
//
#include <hip/hip_runtime.h>
#include <hip/hip_bf16.h>

// GraphSAGE forward: proj -> [aggr -> gemm] x2 (+cls fused into gemm2)
// N=200000, E=3200000, IN_DIM=165, HID=64. All fp32.
//
// R6 design notes (post-mortem R5: scatter_kernel 278us, WRITE_SIZE 203MB =
// 3.2M x 64B -> every random 4B store costs a full line-granule HBM write;
// all 8 non-coherent XCD L2s touch the same 12.8MB region so write-combining
// never happens. Fix: dst-range sharding):
//  - degree/scatter blocks take range r = blockIdx%8 (round-robin block->XCD
//    heuristic) and only process edges with dst in [25000r, 25000(r+1)).
//    Random writes confined to 1.6MB csr + 100KB cursor per range ->
//    L2/L3-resident, 16 writes coalesce per line. Edge list re-read 8x but
//    sequential + cache-absorbed.
//  - gemm tiles: 64x64, stride 64, XOR chunk swizzle (R5).
//  - proj: 64x64 LDS tile, stride 57.
//  - aggregation: 16-lane groups x float4.
//  - cls fused into gemm2 epilogue.

#define NNODES 200000
#define NEDGES 3200000
#define INDIM 165
#define HID 64

#define NR 8                    // dst ranges (= XCD count)
#define RSIZE (NNODES / NR)     // 25000
#define CHUNK_E 4096            // edges per block chunk

#define SCAN_T 256
#define SCAN_I 8
#define SCAN_CHUNK (SCAN_T * SCAN_I)   // 2048

typedef float f4 __attribute__((ext_vector_type(4)));

// ---------------- proj: h = relu(x @ Wp + bp) -----------------------------
#define XS_STRIDE 57

__global__ __launch_bounds__(256, 2)
void proj_kernel(const float* __restrict__ x,
                 const float* __restrict__ Wp,
                 const float* __restrict__ bp,
                 float* __restrict__ h, int n) {
  __shared__ float w_s[INDIM * HID];
  __shared__ float x_s[64 * XS_STRIDE];
  int t = threadIdx.x;
  int tx = t & 15;
  int ny4 = (t >> 4) * 4;
  int n0 = blockIdx.x * 64;

  for (int i = t; i < INDIM * HID / 4; i += 256)
    ((f4*)w_s)[i] = ((const f4*)Wp)[i];

  f4 bv = ((const f4*)bp)[tx];
  f4 acc0 = bv, acc1 = bv, acc2 = bv, acc3 = bv;

  for (int kc = 0; kc < 3; ++kc) {
    for (int i = t; i < 64 * 55; i += 256) {
      int row = i / 55, col = i % 55;
      x_s[row * XS_STRIDE + col] = x[(size_t)(n0 + row) * INDIM + kc * 55 + col];
    }
    __syncthreads();
    #pragma unroll 5
    for (int k = 0; k < 55; ++k) {
      f4 wv = *(const f4*)&w_s[(kc * 55 + k) * HID + tx * 4];
      float x0 = x_s[(ny4 + 0) * XS_STRIDE + k];
      float x1 = x_s[(ny4 + 1) * XS_STRIDE + k];
      float x2 = x_s[(ny4 + 2) * XS_STRIDE + k];
      float x3 = x_s[(ny4 + 3) * XS_STRIDE + k];
      acc0 += x0 * wv; acc1 += x1 * wv; acc2 += x2 * wv; acc3 += x3 * wv;
    }
    __syncthreads();
  }
  acc0.x = fmaxf(acc0.x, 0.f); acc0.y = fmaxf(acc0.y, 0.f); acc0.z = fmaxf(acc0.z, 0.f); acc0.w = fmaxf(acc0.w, 0.f);
  acc1.x = fmaxf(acc1.x, 0.f); acc1.y = fmaxf(acc1.y, 0.f); acc1.z = fmaxf(acc1.z, 0.f); acc1.w = fmaxf(acc1.w, 0.f);
  acc2.x = fmaxf(acc2.x, 0.f); acc2.y = fmaxf(acc2.y, 0.f); acc2.z = fmaxf(acc2.z, 0.f); acc2.w = fmaxf(acc2.w, 0.f);
  acc3.x = fmaxf(acc3.x, 0.f); acc3.y = fmaxf(acc3.y, 0.f); acc3.z = fmaxf(acc3.z, 0.f); acc3.w = fmaxf(acc3.w, 0.f);
  *(f4*)&h[(size_t)(n0 + ny4 + 0) * HID + tx * 4] = acc0;
  *(f4*)&h[(size_t)(n0 + ny4 + 1) * HID + tx * 4] = acc1;
  *(f4*)&h[(size_t)(n0 + ny4 + 2) * HID + tx * 4] = acc2;
  *(f4*)&h[(size_t)(n0 + ny4 + 3) * HID + tx * 4] = acc3;
}

// ---------------- degree histogram (dst-range sharded) --------------------
__global__ void degree_kernel(const int* __restrict__ dst, int* __restrict__ counts, int e) {
  int r = blockIdx.x & (NR - 1);
  int chunk = blockIdx.x / NR;
  int lo = r * RSIZE, hi = lo + RSIZE;
  int base = chunk * CHUNK_E;
  int end = min(base + CHUNK_E, e);
  for (int i = base + (int)threadIdx.x; i < end; i += 256) {
    int d = dst[i];
    if (d >= lo && d < hi) atomicAdd(&counts[d], 1);
  }
}

// ---------------- scan ----------------------------------------------------
__global__ void scan1_kernel(const int* __restrict__ counts, int* __restrict__ row_ptr,
                             int* __restrict__ bsums, int n) {
  __shared__ int lds[SCAN_T];
  int b = blockIdx.x, t = threadIdx.x;
  int base = b * SCAN_CHUNK + t * SCAN_I;
  int v[SCAN_I];
  int s = 0;
  #pragma unroll
  for (int i = 0; i < SCAN_I; ++i) {
    int idx = base + i;
    v[i] = (idx < n) ? counts[idx] : 0;
    s += v[i];
  }
  lds[t] = s;
  __syncthreads();
  for (int off = 1; off < SCAN_T; off <<= 1) {
    int y = (t >= off) ? lds[t - off] : 0;
    __syncthreads();
    lds[t] += y;
    __syncthreads();
  }
  int incl = lds[t];
  int run = incl - s;
  #pragma unroll
  for (int i = 0; i < SCAN_I; ++i) {
    int idx = base + i;
    if (idx < n) row_ptr[idx] = run;
    run += v[i];
  }
  if (t == SCAN_T - 1) bsums[b] = incl;
}

__global__ void scan2_kernel(int* __restrict__ bsums, int nb) {
  __shared__ int lds[SCAN_T];
  int t = threadIdx.x;
  int v = (t < nb) ? bsums[t] : 0;
  lds[t] = v;
  __syncthreads();
  for (int off = 1; off < SCAN_T; off <<= 1) {
    int y = (t >= off) ? lds[t - off] : 0;
    __syncthreads();
    lds[t] += y;
    __syncthreads();
  }
  if (t < nb) bsums[t] = lds[t] - v;
}

__global__ void scan3_kernel(int* __restrict__ row_ptr, const int* __restrict__ bsums,
                             int* __restrict__ cursor, int n, int e) {
  int i = blockIdx.x * blockDim.x + threadIdx.x;
  if (i < n) {
    int v = row_ptr[i] + bsums[i / SCAN_CHUNK];
    row_ptr[i] = v;
    cursor[i] = v;
  }
  if (i == n) row_ptr[n] = e;
}

// ---------------- scatter edges into CSR (dst-range sharded) --------------
__global__ void scatter_kernel(const int* __restrict__ src, const int* __restrict__ dst,
                               int* __restrict__ cursor, int* __restrict__ csr_src, int e) {
  int r = blockIdx.x & (NR - 1);
  int chunk = blockIdx.x / NR;
  int lo = r * RSIZE, hi = lo + RSIZE;
  int base = chunk * CHUNK_E;
  int end = min(base + CHUNK_E, e);
  for (int i = base + (int)threadIdx.x; i < end; i += 256) {
    int d = dst[i];
    if (d >= lo && d < hi) {
      int pos = atomicAdd(&cursor[d], 1);
      csr_src[pos] = src[i];
    }
  }
}

// ---------------- mean aggregation (pull, CSR) ----------------------------
__global__ void aggr_kernel(const float* __restrict__ hin,
                            const int* __restrict__ row_ptr,
                            const int* __restrict__ csr_src,
                            float* __restrict__ aggr, int n) {
  int lane = threadIdx.x & 63;
  int grp = lane >> 4, sub = lane & 15;
  int node = (blockIdx.x * blockDim.x + threadIdx.x) >> 6;
  if (node >= n) return;
  int r0 = row_ptr[node], r1 = row_ptr[node + 1];
  f4 acc0 = {0.f, 0.f, 0.f, 0.f}, acc1 = {0.f, 0.f, 0.f, 0.f};
  int p = r0;
  for (; p + 8 <= r1; p += 8) {
    int i0 = csr_src[p + grp];
    int i1 = csr_src[p + 4 + grp];
    f4 v0 = *((const f4*)(hin + (size_t)i0 * HID) + sub);
    f4 v1 = *((const f4*)(hin + (size_t)i1 * HID) + sub);
    acc0 += v0;
    acc1 += v1;
  }
  if (p + 4 <= r1) {
    int i0 = csr_src[p + grp];
    acc0 += *((const f4*)(hin + (size_t)i0 * HID) + sub);
    p += 4;
  }
  int rem = r1 - p;
  if (grp < rem) {
    int i0 = csr_src[p + grp];
    acc1 += *((const f4*)(hin + (size_t)i0 * HID) + sub);
  }
  acc0 += acc1;
  #pragma unroll
  for (int c = 0; c < 4; ++c) {
    float v = acc0[c];
    v += __shfl_xor(v, 16, 64);
    v += __shfl_xor(v, 32, 64);
    acc0[c] = v;
  }
  int deg = r1 - r0;
  float rdeg = 1.f / (float)(deg > 1 ? deg : 1);
  if (grp == 0) {
    f4 o = acc0 * rdeg;
    *((f4*)(aggr + (size_t)node * HID) + sub) = o;
  }
}

// ---------------- gemm: hout = relu(aggr@Wl + bl + hin@Wr) ---------------
#define GEMM_STAGE(aggrp, hinp) \
  for (int i = t; i < HID * HID / 4; i += 256) { \
    ((f4*)wl_s)[i] = ((const f4*)Wl)[i]; \
    ((f4*)wr_s)[i] = ((const f4*)Wr)[i]; \
  } \
  for (int i = t; i < 64 * 16; i += 256) { \
    int row = i >> 4, c4 = i & 15; \
    int cs = c4 ^ ((row >> 2) & 3); \
    ((f4*)a_s)[row * 16 + cs] = ((const f4*)(aggrp + (size_t)(n0 + row) * HID))[c4]; \
    ((f4*)h_s)[row * 16 + cs] = ((const f4*)(hinp + (size_t)(n0 + row) * HID))[c4]; \
  } \
  __syncthreads();

#define GEMM_KLOOP() \
  _Pragma("unroll 4") \
  for (int kc = 0; kc < 16; ++kc) { \
    int k = kc * 4; \
    f4 wl0 = *(const f4*)&wl_s[(k+0) * HID + tx * 4]; \
    f4 wl1 = *(const f4*)&wl_s[(k+1) * HID + tx * 4]; \
    f4 wl2 = *(const f4*)&wl_s[(k+2) * HID + tx * 4]; \
    f4 wl3 = *(const f4*)&wl_s[(k+3) * HID + tx * 4]; \
    f4 wr0 = *(const f4*)&wr_s[(k+0) * HID + tx * 4]; \
    f4 wr1 = *(const f4*)&wr_s[(k+1) * HID + tx * 4]; \
    f4 wr2 = *(const f4*)&wr_s[(k+2) * HID + tx * 4]; \
    f4 wr3 = *(const f4*)&wr_s[(k+3) * HID + tx * 4]; \
    int cs = kc ^ q3; \
    f4 av0 = ((const f4*)a_s)[(ny4 + 0) * 16 + cs]; \
    f4 av1 = ((const f4*)a_s)[(ny4 + 1) * 16 + cs]; \
    f4 av2 = ((const f4*)a_s)[(ny4 + 2) * 16 + cs]; \
    f4 av3 = ((const f4*)a_s)[(ny4 + 3) * 16 + cs]; \
    f4 hv0 = ((const f4*)h_s)[(ny4 + 0) * 16 + cs]; \
    f4 hv1 = ((const f4*)h_s)[(ny4 + 1) * 16 + cs]; \
    f4 hv2 = ((const f4*)h_s)[(ny4 + 2) * 16 + cs]; \
    f4 hv3 = ((const f4*)h_s)[(ny4 + 3) * 16 + cs]; \
    acc0 += av0.x * wl0 + av0.y * wl1 + av0.z * wl2 + av0.w * wl3 \
          + hv0.x * wr0 + hv0.y * wr1 + hv0.z * wr2 + hv0.w * wr3; \
    acc1 += av1.x * wl0 + av1.y * wl1 + av1.z * wl2 + av1.w * wl3 \
          + hv1.x * wr0 + hv1.y * wr1 + hv1.z * wr2 + hv1.w * wr3; \
    acc2 += av2.x * wl0 + av2.y * wl1 + av2.z * wl2 + av2.w * wl3 \
          + hv2.x * wr0 + hv2.y * wr1 + hv2.z * wr2 + hv2.w * wr3; \
    acc3 += av3.x * wl0 + av3.y * wl1 + av3.z * wl2 + av3.w * wl3 \
          + hv3.x * wr0 + hv3.y * wr1 + hv3.z * wr2 + hv3.w * wr3; \
  }

__global__ __launch_bounds__(256, 2)
void gemm_kernel(const float* __restrict__ aggr,
                 const float* hin,
                 const float* __restrict__ Wl, const float* __restrict__ bl,
                 const float* __restrict__ Wr,
                 float* hout, int n) {
  __shared__ float wl_s[HID * HID];
  __shared__ float wr_s[HID * HID];
  __shared__ float a_s[64 * 64];
  __shared__ float h_s[64 * 64];
  int t = threadIdx.x;
  int tx = t & 15;
  int ny4 = (t >> 4) * 4;
  int q3 = (t >> 4) & 3;
  int n0 = blockIdx.x * 64;

  GEMM_STAGE(aggr, hin)

  f4 bv = ((const f4*)bl)[tx];
  f4 acc0 = bv, acc1 = bv, acc2 = bv, acc3 = bv;
  GEMM_KLOOP()

  acc0.x = fmaxf(acc0.x, 0.f); acc0.y = fmaxf(acc0.y, 0.f); acc0.z = fmaxf(acc0.z, 0.f); acc0.w = fmaxf(acc0.w, 0.f);
  acc1.x = fmaxf(acc1.x, 0.f); acc1.y = fmaxf(acc1.y, 0.f); acc1.z = fmaxf(acc1.z, 0.f); acc1.w = fmaxf(acc1.w, 0.f);
  acc2.x = fmaxf(acc2.x, 0.f); acc2.y = fmaxf(acc2.y, 0.f); acc2.z = fmaxf(acc2.z, 0.f); acc2.w = fmaxf(acc2.w, 0.f);
  acc3.x = fmaxf(acc3.x, 0.f); acc3.y = fmaxf(acc3.y, 0.f); acc3.z = fmaxf(acc3.z, 0.f); acc3.w = fmaxf(acc3.w, 0.f);
  *(f4*)&hout[(size_t)(n0 + ny4 + 0) * HID + tx * 4] = acc0;
  *(f4*)&hout[(size_t)(n0 + ny4 + 1) * HID + tx * 4] = acc1;
  *(f4*)&hout[(size_t)(n0 + ny4 + 2) * HID + tx * 4] = acc2;
  *(f4*)&hout[(size_t)(n0 + ny4 + 3) * HID + tx * 4] = acc3;
}

// ---------------- gemm2 + cls fused ---------------------------------------
__global__ __launch_bounds__(256, 2)
void gemm_cls_kernel(const float* __restrict__ aggr,
                     const float* __restrict__ hin,
                     const float* __restrict__ Wl, const float* __restrict__ bl,
                     const float* __restrict__ Wr,
                     const float* __restrict__ Wc, const float* __restrict__ bc,
                     float* __restrict__ out, int n) {
  __shared__ float wl_s[HID * HID];
  __shared__ float wr_s[HID * HID];
  __shared__ float a_s[64 * 64];
  __shared__ float h_s[64 * 64];
  int t = threadIdx.x;
  int tx = t & 15;
  int ny4 = (t >> 4) * 4;
  int q3 = (t >> 4) & 3;
  int n0 = blockIdx.x * 64;

  GEMM_STAGE(aggr, hin)

  f4 bv = ((const f4*)bl)[tx];
  f4 acc0 = bv, acc1 = bv, acc2 = bv, acc3 = bv;
  GEMM_KLOOP()

  f4 wcv = ((const f4*)Wc)[tx];
  float bcv = bc[0];
  float s0 = fmaxf(acc0.x,0.f)*wcv.x + fmaxf(acc0.y,0.f)*wcv.y + fmaxf(acc0.z,0.f)*wcv.z + fmaxf(acc0.w,0.f)*wcv.w;
  float s1 = fmaxf(acc1.x,0.f)*wcv.x + fmaxf(acc1.y,0.f)*wcv.y + fmaxf(acc1.z,0.f)*wcv.z + fmaxf(acc1.w,0.f)*wcv.w;
  float s2 = fmaxf(acc2.x,0.f)*wcv.x + fmaxf(acc2.y,0.f)*wcv.y + fmaxf(acc2.z,0.f)*wcv.z + fmaxf(acc2.w,0.f)*wcv.w;
  float s3 = fmaxf(acc3.x,0.f)*wcv.x + fmaxf(acc3.y,0.f)*wcv.y + fmaxf(acc3.z,0.f)*wcv.z + fmaxf(acc3.w,0.f)*wcv.w;
  #pragma unroll
  for (int off = 1; off < 16; off <<= 1) {
    s0 += __shfl_xor(s0, off, 64);
    s1 += __shfl_xor(s1, off, 64);
    s2 += __shfl_xor(s2, off, 64);
    s3 += __shfl_xor(s3, off, 64);
  }
  if (tx == 0) {
    out[n0 + ny4 + 0] = s0 + bcv;
    out[n0 + ny4 + 1] = s1 + bcv;
    out[n0 + ny4 + 2] = s2 + bcv;
    out[n0 + ny4 + 3] = s3 + bcv;
  }
}

extern "C" void kernel_launch(void* const* d_in, const int* in_sizes, int n_in,
                              void* d_out, int out_size, void* d_ws, size_t ws_size,
                              hipStream_t stream) {
  const float* x   = (const float*)d_in[0];
  const int*   ei  = (const int*)d_in[1];
  const float* Wp  = (const float*)d_in[2];
  const float* bp  = (const float*)d_in[3];
  const float* W1l = (const float*)d_in[4];
  const float* b1l = (const float*)d_in[5];
  const float* W1r = (const float*)d_in[6];
  const float* W2l = (const float*)d_in[7];
  const float* b2l = (const float*)d_in[8];
  const float* W2r = (const float*)d_in[9];
  const float* Wc  = (const float*)d_in[10];
  const float* bc  = (const float*)d_in[11];
  float* out = (float*)d_out;

  const int N = NNODES, E = NEDGES;
  const int* src = ei;
  const int* dst = ei + E;

  char* ws = (char*)d_ws;
  float* h       = (float*)(ws + 0);                 // 51,200,000 B
  float* aggr    = (float*)(ws + 51200000);          // 51,200,000 B
  int*   counts  = (int*)  (ws + 102400000);         // 800,000
  int*   row_ptr = (int*)  (ws + 103200000);         // 800,004 (padded)
  int*   cursor  = (int*)  (ws + 104000256);         // 800,000
  int*   csr_src = (int*)  (ws + 104800256);         // 12,800,000
  int*   bsums   = (int*)  (ws + 117600256);         // small

  hipMemsetAsync(counts, 0, (size_t)N * 4, stream);

  // proj: 200000/64 = 3125 blocks
  proj_kernel<<<3125, 256, 0, stream>>>(x, Wp, bp, h, N);

  // CSR build (degree/scatter dst-range sharded: blockIdx%8 = range ~ XCD)
  int nchunks = (E + CHUNK_E - 1) / CHUNK_E;  // 782
  degree_kernel<<<nchunks * NR, 256, 0, stream>>>(dst, counts, E);
  int nb = (N + SCAN_CHUNK - 1) / SCAN_CHUNK;  // 98
  scan1_kernel<<<nb, SCAN_T, 0, stream>>>(counts, row_ptr, bsums, N);
  scan2_kernel<<<1, SCAN_T, 0, stream>>>(bsums, nb);
  scan3_kernel<<<(N + 256) / 256, 256, 0, stream>>>(row_ptr, bsums, cursor, N, E);
  scatter_kernel<<<nchunks * NR, 256, 0, stream>>>(src, dst, cursor, csr_src, E);

  // layer 1
  aggr_kernel<<<(N + 3) / 4, 256, 0, stream>>>(h, row_ptr, csr_src, aggr, N);
  gemm_kernel<<<3125, 256, 0, stream>>>(aggr, h, W1l, b1l, W1r, h, N);

  // layer 2 + cls
  aggr_kernel<<<(N + 3) / 4, 256, 0, stream>>>(h, row_ptr, csr_src, aggr, N);
  gemm_cls_kernel<<<3125, 256, 0, stream>>>(aggr, h, W2l, b2l, W2r, Wc, bc, out, N);
}

// Round 7
// 1021.799 us; speedup vs baseline: 3.5074x; 1.0176x over previous
//
#include <hip/hip_runtime.h>
#include <hip/hip_bf16.h>

// GraphSAGE forward: proj -> [aggr -> gemm] x2 (+cls fused into gemm2)
// N=200000, E=3200000, IN_DIM=165, HID=64. All fp32.
//
// R7 design notes (post-mortem R6: proj VALUBusy 19% = LDS-issue-bound;
// 4x4 micro-tile gives only 2-4 FMAs per LDS dword, ratio LDS:VALU = 4.4).
//  - matmuls: block = 256 nodes x 64 outs, thread = 8 nodes x 8 outs
//    (16 f4 accs). x-side staged TRANSPOSED x_s[k][node] @ stride 260
//    (f4-aligned, (260%32)=4 -> 2-way max bank aliasing = free) so node-dim
//    reads are b128. Per k per wave: 4 b128 = 48 LDS cyc vs 32 per-CU VALU
//    cyc -> ratio 1.5 -> ~65% VALU ceiling (was 19%).
//  - W chunks (BK rows) restaged per chunk -> small LDS, occupancy up.
//  - degree/scatter dst-range sharded (R6). cls fused into gemm2.

#define NNODES 200000
#define NEDGES 3200000
#define INDIM 165
#define HID 64

#define NR 8
#define RSIZE (NNODES / NR)
#define CHUNK_E 4096

#define SCAN_T 256
#define SCAN_I 8
#define SCAN_CHUNK (SCAN_T * SCAN_I)

#define BKP 15            // proj K chunk: 165 = 11*15
#define BKG 16            // gemm K chunk: 64 = 4*16
#define XT_STRIDE 260     // >=256 nodes, %4==0 (f4 aligned), %32==4 (bank rotate)

typedef float f4 __attribute__((ext_vector_type(4)));

#define RELU4(v) { v.x=fmaxf(v.x,0.f); v.y=fmaxf(v.y,0.f); v.z=fmaxf(v.z,0.f); v.w=fmaxf(v.w,0.f); }

// 8 nodes x 8 outs micro-tile FMA for one k (x from xv0/xv1, w wv0/wv1)
#define MT_FMA(xv0, xv1, wv0, wv1) \
  accA[0] += xv0.x * wv0; accB[0] += xv0.x * wv1; \
  accA[1] += xv0.y * wv0; accB[1] += xv0.y * wv1; \
  accA[2] += xv0.z * wv0; accB[2] += xv0.z * wv1; \
  accA[3] += xv0.w * wv0; accB[3] += xv0.w * wv1; \
  accA[4] += xv1.x * wv0; accB[4] += xv1.x * wv1; \
  accA[5] += xv1.y * wv0; accB[5] += xv1.y * wv1; \
  accA[6] += xv1.z * wv0; accB[6] += xv1.z * wv1; \
  accA[7] += xv1.w * wv0; accB[7] += xv1.w * wv1;

// ---------------- proj: h = relu(x @ Wp + bp) -----------------------------
__global__ __launch_bounds__(256, 3)
void proj_kernel(const float* __restrict__ x,
                 const float* __restrict__ Wp,
                 const float* __restrict__ bp,
                 float* __restrict__ h, int n) {
  __shared__ float x_s[BKP * XT_STRIDE];   // 15,600 B
  __shared__ float w_s[BKP * HID];         //  3,840 B
  int t = threadIdx.x;
  int tx = t & 7;        // out octet j = tx*8 .. +7
  int ng = t >> 3;       // node group: nodes ng*8 .. +7 (0..31)
  int n0 = blockIdx.x * 256;

  f4 b0 = ((const f4*)bp)[tx * 2];
  f4 b1 = ((const f4*)bp)[tx * 2 + 1];
  f4 accA[8], accB[8];
  #pragma unroll
  for (int i = 0; i < 8; ++i) { accA[i] = b0; accB[i] = b1; }

  for (int kc = 0; kc < INDIM / BKP; ++kc) {
    #pragma unroll
    for (int i = t; i < 256 * BKP; i += 256) {
      int node = i / BKP, col = i % BKP;
      int gi = n0 + node; if (gi >= n) gi = n - 1;
      x_s[col * XT_STRIDE + node] = x[(size_t)gi * INDIM + kc * BKP + col];
    }
    if (t < BKP * HID / 4)
      ((f4*)w_s)[t] = ((const f4*)(Wp + kc * BKP * HID))[t];
    __syncthreads();
    #pragma unroll
    for (int k = 0; k < BKP; ++k) {
      const float* xr = &x_s[k * XT_STRIDE + ng * 8];
      f4 xv0 = *(const f4*)xr;
      f4 xv1 = *(const f4*)(xr + 4);
      f4 wv0 = *(const f4*)&w_s[k * HID + tx * 8];
      f4 wv1 = *(const f4*)&w_s[k * HID + tx * 8 + 4];
      MT_FMA(xv0, xv1, wv0, wv1)
    }
    __syncthreads();
  }
  #pragma unroll
  for (int i = 0; i < 8; ++i) {
    int node = n0 + ng * 8 + i;
    if (node < n) {
      f4 a = accA[i], b = accB[i];
      RELU4(a) RELU4(b)
      *(f4*)&h[(size_t)node * HID + tx * 8] = a;
      *(f4*)&h[(size_t)node * HID + tx * 8 + 4] = b;
    }
  }
}

// ---------------- degree histogram (dst-range sharded) --------------------
__global__ void degree_kernel(const int* __restrict__ dst, int* __restrict__ counts, int e) {
  int r = blockIdx.x & (NR - 1);
  int chunk = blockIdx.x / NR;
  int lo = r * RSIZE, hi = lo + RSIZE;
  int base = chunk * CHUNK_E;
  int end = min(base + CHUNK_E, e);
  for (int i = base + (int)threadIdx.x; i < end; i += 256) {
    int d = dst[i];
    if (d >= lo && d < hi) atomicAdd(&counts[d], 1);
  }
}

// ---------------- scan ----------------------------------------------------
__global__ void scan1_kernel(const int* __restrict__ counts, int* __restrict__ row_ptr,
                             int* __restrict__ bsums, int n) {
  __shared__ int lds[SCAN_T];
  int b = blockIdx.x, t = threadIdx.x;
  int base = b * SCAN_CHUNK + t * SCAN_I;
  int v[SCAN_I];
  int s = 0;
  #pragma unroll
  for (int i = 0; i < SCAN_I; ++i) {
    int idx = base + i;
    v[i] = (idx < n) ? counts[idx] : 0;
    s += v[i];
  }
  lds[t] = s;
  __syncthreads();
  for (int off = 1; off < SCAN_T; off <<= 1) {
    int y = (t >= off) ? lds[t - off] : 0;
    __syncthreads();
    lds[t] += y;
    __syncthreads();
  }
  int incl = lds[t];
  int run = incl - s;
  #pragma unroll
  for (int i = 0; i < SCAN_I; ++i) {
    int idx = base + i;
    if (idx < n) row_ptr[idx] = run;
    run += v[i];
  }
  if (t == SCAN_T - 1) bsums[b] = incl;
}

__global__ void scan2_kernel(int* __restrict__ bsums, int nb) {
  __shared__ int lds[SCAN_T];
  int t = threadIdx.x;
  int v = (t < nb) ? bsums[t] : 0;
  lds[t] = v;
  __syncthreads();
  for (int off = 1; off < SCAN_T; off <<= 1) {
    int y = (t >= off) ? lds[t - off] : 0;
    __syncthreads();
    lds[t] += y;
    __syncthreads();
  }
  if (t < nb) bsums[t] = lds[t] - v;
}

__global__ void scan3_kernel(int* __restrict__ row_ptr, const int* __restrict__ bsums,
                             int* __restrict__ cursor, int n, int e) {
  int i = blockIdx.x * blockDim.x + threadIdx.x;
  if (i < n) {
    int v = row_ptr[i] + bsums[i / SCAN_CHUNK];
    row_ptr[i] = v;
    cursor[i] = v;
  }
  if (i == n) row_ptr[n] = e;
}

// ---------------- scatter edges into CSR (dst-range sharded) --------------
__global__ void scatter_kernel(const int* __restrict__ src, const int* __restrict__ dst,
                               int* __restrict__ cursor, int* __restrict__ csr_src, int e) {
  int r = blockIdx.x & (NR - 1);
  int chunk = blockIdx.x / NR;
  int lo = r * RSIZE, hi = lo + RSIZE;
  int base = chunk * CHUNK_E;
  int end = min(base + CHUNK_E, e);
  for (int i = base + (int)threadIdx.x; i < end; i += 256) {
    int d = dst[i];
    if (d >= lo && d < hi) {
      int pos = atomicAdd(&cursor[d], 1);
      csr_src[pos] = src[i];
    }
  }
}

// ---------------- mean aggregation (pull, CSR) ----------------------------
__global__ void aggr_kernel(const float* __restrict__ hin,
                            const int* __restrict__ row_ptr,
                            const int* __restrict__ csr_src,
                            float* __restrict__ aggr, int n) {
  int lane = threadIdx.x & 63;
  int grp = lane >> 4, sub = lane & 15;
  int node = (blockIdx.x * blockDim.x + threadIdx.x) >> 6;
  if (node >= n) return;
  int r0 = row_ptr[node], r1 = row_ptr[node + 1];
  f4 acc0 = {0.f, 0.f, 0.f, 0.f}, acc1 = {0.f, 0.f, 0.f, 0.f};
  int p = r0;
  for (; p + 8 <= r1; p += 8) {
    int i0 = csr_src[p + grp];
    int i1 = csr_src[p + 4 + grp];
    f4 v0 = *((const f4*)(hin + (size_t)i0 * HID) + sub);
    f4 v1 = *((const f4*)(hin + (size_t)i1 * HID) + sub);
    acc0 += v0;
    acc1 += v1;
  }
  if (p + 4 <= r1) {
    int i0 = csr_src[p + grp];
    acc0 += *((const f4*)(hin + (size_t)i0 * HID) + sub);
    p += 4;
  }
  int rem = r1 - p;
  if (grp < rem) {
    int i0 = csr_src[p + grp];
    acc1 += *((const f4*)(hin + (size_t)i0 * HID) + sub);
  }
  acc0 += acc1;
  #pragma unroll
  for (int c = 0; c < 4; ++c) {
    float v = acc0[c];
    v += __shfl_xor(v, 16, 64);
    v += __shfl_xor(v, 32, 64);
    acc0[c] = v;
  }
  int deg = r1 - r0;
  float rdeg = 1.f / (float)(deg > 1 ? deg : 1);
  if (grp == 0) {
    f4 o = acc0 * rdeg;
    *((f4*)(aggr + (size_t)node * HID) + sub) = o;
  }
}

// ---------------- gemm: hout = relu(aggr@Wl + bl + hin@Wr) ---------------
// block = 256 nodes x 64 outs; thread = 8 nodes x 8 outs; BK=16 chunks.
// In-place hout==hin safe: all stores in epilogue, block writes only its rows.

#define GEMM_BODY(aggrp, hinp) \
  for (int kc = 0; kc < HID / BKG; ++kc) { \
    _Pragma("unroll") \
    for (int i = t; i < 256 * BKG; i += 256) { \
      int node = i >> 4, k = i & 15; \
      int gi = n0 + node; if (gi >= n) gi = n - 1; \
      a_s[k * XT_STRIDE + node] = aggrp[(size_t)gi * HID + kc * BKG + k]; \
      h_s[k * XT_STRIDE + node] = hinp[(size_t)gi * HID + kc * BKG + k]; \
    } \
    if (t < BKG * HID / 4) { \
      ((f4*)wl_s)[t] = ((const f4*)(Wl + kc * BKG * HID))[t]; \
      ((f4*)wr_s)[t] = ((const f4*)(Wr + kc * BKG * HID))[t]; \
    } \
    __syncthreads(); \
    _Pragma("unroll") \
    for (int k = 0; k < BKG; ++k) { \
      const float* ar = &a_s[k * XT_STRIDE + ng * 8]; \
      const float* hr = &h_s[k * XT_STRIDE + ng * 8]; \
      f4 av0 = *(const f4*)ar; \
      f4 av1 = *(const f4*)(ar + 4); \
      f4 hv0 = *(const f4*)hr; \
      f4 hv1 = *(const f4*)(hr + 4); \
      f4 wl0 = *(const f4*)&wl_s[k * HID + tx * 8]; \
      f4 wl1 = *(const f4*)&wl_s[k * HID + tx * 8 + 4]; \
      f4 wr0 = *(const f4*)&wr_s[k * HID + tx * 8]; \
      f4 wr1 = *(const f4*)&wr_s[k * HID + tx * 8 + 4]; \
      accA[0] += av0.x * wl0 + hv0.x * wr0;  accB[0] += av0.x * wl1 + hv0.x * wr1; \
      accA[1] += av0.y * wl0 + hv0.y * wr0;  accB[1] += av0.y * wl1 + hv0.y * wr1; \
      accA[2] += av0.z * wl0 + hv0.z * wr0;  accB[2] += av0.z * wl1 + hv0.z * wr1; \
      accA[3] += av0.w * wl0 + hv0.w * wr0;  accB[3] += av0.w * wl1 + hv0.w * wr1; \
      accA[4] += av1.x * wl0 + hv1.x * wr0;  accB[4] += av1.x * wl1 + hv1.x * wr1; \
      accA[5] += av1.y * wl0 + hv1.y * wr0;  accB[5] += av1.y * wl1 + hv1.y * wr1; \
      accA[6] += av1.z * wl0 + hv1.z * wr0;  accB[6] += av1.z * wl1 + hv1.z * wr1; \
      accA[7] += av1.w * wl0 + hv1.w * wr0;  accB[7] += av1.w * wl1 + hv1.w * wr1; \
    } \
    __syncthreads(); \
  }

__global__ __launch_bounds__(256, 3)
void gemm_kernel(const float* __restrict__ aggr,
                 const float* hin,
                 const float* __restrict__ Wl, const float* __restrict__ bl,
                 const float* __restrict__ Wr,
                 float* hout, int n) {
  __shared__ float a_s[BKG * XT_STRIDE];   // 16,640 B
  __shared__ float h_s[BKG * XT_STRIDE];   // 16,640 B
  __shared__ float wl_s[BKG * HID];        //  4,096 B
  __shared__ float wr_s[BKG * HID];        //  4,096 B  (total 41,472)
  int t = threadIdx.x;
  int tx = t & 7;
  int ng = t >> 3;
  int n0 = blockIdx.x * 256;

  f4 b0 = ((const f4*)bl)[tx * 2];
  f4 b1 = ((const f4*)bl)[tx * 2 + 1];
  f4 accA[8], accB[8];
  #pragma unroll
  for (int i = 0; i < 8; ++i) { accA[i] = b0; accB[i] = b1; }

  GEMM_BODY(aggr, hin)

  #pragma unroll
  for (int i = 0; i < 8; ++i) {
    int node = n0 + ng * 8 + i;
    if (node < n) {
      f4 a = accA[i], b = accB[i];
      RELU4(a) RELU4(b)
      *(f4*)&hout[(size_t)node * HID + tx * 8] = a;
      *(f4*)&hout[(size_t)node * HID + tx * 8 + 4] = b;
    }
  }
}

// ---------------- gemm2 + cls fused ---------------------------------------
__global__ __launch_bounds__(256, 3)
void gemm_cls_kernel(const float* __restrict__ aggr,
                     const float* __restrict__ hin,
                     const float* __restrict__ Wl, const float* __restrict__ bl,
                     const float* __restrict__ Wr,
                     const float* __restrict__ Wc, const float* __restrict__ bc,
                     float* __restrict__ out, int n) {
  __shared__ float a_s[BKG * XT_STRIDE];
  __shared__ float h_s[BKG * XT_STRIDE];
  __shared__ float wl_s[BKG * HID];
  __shared__ float wr_s[BKG * HID];
  int t = threadIdx.x;
  int tx = t & 7;
  int ng = t >> 3;
  int n0 = blockIdx.x * 256;

  f4 b0 = ((const f4*)bl)[tx * 2];
  f4 b1 = ((const f4*)bl)[tx * 2 + 1];
  f4 accA[8], accB[8];
  #pragma unroll
  for (int i = 0; i < 8; ++i) { accA[i] = b0; accB[i] = b1; }

  GEMM_BODY(aggr, hin)

  f4 wc0 = ((const f4*)Wc)[tx * 2];
  f4 wc1 = ((const f4*)Wc)[tx * 2 + 1];
  float bcv = bc[0];
  #pragma unroll
  for (int i = 0; i < 8; ++i) {
    f4 a = accA[i], b = accB[i];
    RELU4(a) RELU4(b)
    float s = a.x * wc0.x + a.y * wc0.y + a.z * wc0.z + a.w * wc0.w
            + b.x * wc1.x + b.y * wc1.y + b.z * wc1.z + b.w * wc1.w;
    // reduce across the 8 tx lanes (low 3 bits of lane id)
    s += __shfl_xor(s, 1, 64);
    s += __shfl_xor(s, 2, 64);
    s += __shfl_xor(s, 4, 64);
    int node = n0 + ng * 8 + i;
    if (tx == 0 && node < n) out[node] = s + bcv;
  }
}

extern "C" void kernel_launch(void* const* d_in, const int* in_sizes, int n_in,
                              void* d_out, int out_size, void* d_ws, size_t ws_size,
                              hipStream_t stream) {
  const float* x   = (const float*)d_in[0];
  const int*   ei  = (const int*)d_in[1];
  const float* Wp  = (const float*)d_in[2];
  const float* bp  = (const float*)d_in[3];
  const float* W1l = (const float*)d_in[4];
  const float* b1l = (const float*)d_in[5];
  const float* W1r = (const float*)d_in[6];
  const float* W2l = (const float*)d_in[7];
  const float* b2l = (const float*)d_in[8];
  const float* W2r = (const float*)d_in[9];
  const float* Wc  = (const float*)d_in[10];
  const float* bc  = (const float*)d_in[11];
  float* out = (float*)d_out;

  const int N = NNODES, E = NEDGES;
  const int* src = ei;
  const int* dst = ei + E;

  char* ws = (char*)d_ws;
  float* h       = (float*)(ws + 0);                 // 51,200,000 B
  float* aggr    = (float*)(ws + 51200000);          // 51,200,000 B
  int*   counts  = (int*)  (ws + 102400000);         // 800,000
  int*   row_ptr = (int*)  (ws + 103200000);         // 800,004 (padded)
  int*   cursor  = (int*)  (ws + 104000256);         // 800,000
  int*   csr_src = (int*)  (ws + 104800256);         // 12,800,000
  int*   bsums   = (int*)  (ws + 117600256);         // small

  hipMemsetAsync(counts, 0, (size_t)N * 4, stream);

  // proj: ceil(200000/256) = 782 blocks
  proj_kernel<<<782, 256, 0, stream>>>(x, Wp, bp, h, N);

  // CSR build (dst-range sharded)
  int nchunks = (E + CHUNK_E - 1) / CHUNK_E;
  degree_kernel<<<nchunks * NR, 256, 0, stream>>>(dst, counts, E);
  int nb = (N + SCAN_CHUNK - 1) / SCAN_CHUNK;
  scan1_kernel<<<nb, SCAN_T, 0, stream>>>(counts, row_ptr, bsums, N);
  scan2_kernel<<<1, SCAN_T, 0, stream>>>(bsums, nb);
  scan3_kernel<<<(N + 256) / 256, 256, 0, stream>>>(row_ptr, bsums, cursor, N, E);
  scatter_kernel<<<nchunks * NR, 256, 0, stream>>>(src, dst, cursor, csr_src, E);

  // layer 1
  aggr_kernel<<<(N + 3) / 4, 256, 0, stream>>>(h, row_ptr, csr_src, aggr, N);
  gemm_kernel<<<782, 256, 0, stream>>>(aggr, h, W1l, b1l, W1r, h, N);

  // layer 2 + cls
  aggr_kernel<<<(N + 3) / 4, 256, 0, stream>>>(h, row_ptr, csr_src, aggr, N);
  gemm_cls_kernel<<<782, 256, 0, stream>>>(aggr, h, W2l, b2l, W2r, Wc, bc, out, N);
}

// Round 8
// 1014.400 us; speedup vs baseline: 3.5330x; 1.0073x over previous
//
#include <hip/hip_runtime.h>
#include <hip/hip_bf16.h>

// GraphSAGE forward: proj -> [aggr -> gemm] x2 (+cls fused into gemm2)
// N=200000, E=3200000, IN_DIM=165, HID=64. All fp32.
//
// R8 design notes (post-mortem R7: scatter WRITE_SIZE stayed 203MB despite
// dst-range sharding -> the 102MB/pass dst/src read stream thrashes the 4MiB
// XCD L2, evicting partially-filled dirty csr lines before their 16 edges
// arrive. Fix: __builtin_nontemporal_load on the edge-list streams in
// degree/scatter so only the 1.6MB csr slice + 100KB cursor slice live in
// L2 -> dirty lines accumulate all 16 writes, write back once).
//  - matmuls: 256-node x 64-out blocks, 8x8 micro-tile, transposed x_s (R7).
//  - degree/scatter dst-range sharded (R6) + NT edge reads (R8).
//  - cls fused into gemm2.

#define NNODES 200000
#define NEDGES 3200000
#define INDIM 165
#define HID 64

#define NR 8
#define RSIZE (NNODES / NR)
#define CHUNK_E 4096

#define SCAN_T 256
#define SCAN_I 8
#define SCAN_CHUNK (SCAN_T * SCAN_I)

#define BKP 15            // proj K chunk: 165 = 11*15
#define BKG 16            // gemm K chunk: 64 = 4*16
#define XT_STRIDE 260     // >=256 nodes, %4==0 (f4 aligned), %32==4 (bank rotate)

typedef float f4 __attribute__((ext_vector_type(4)));

#define RELU4(v) { v.x=fmaxf(v.x,0.f); v.y=fmaxf(v.y,0.f); v.z=fmaxf(v.z,0.f); v.w=fmaxf(v.w,0.f); }

#define MT_FMA(xv0, xv1, wv0, wv1) \
  accA[0] += xv0.x * wv0; accB[0] += xv0.x * wv1; \
  accA[1] += xv0.y * wv0; accB[1] += xv0.y * wv1; \
  accA[2] += xv0.z * wv0; accB[2] += xv0.z * wv1; \
  accA[3] += xv0.w * wv0; accB[3] += xv0.w * wv1; \
  accA[4] += xv1.x * wv0; accB[4] += xv1.x * wv1; \
  accA[5] += xv1.y * wv0; accB[5] += xv1.y * wv1; \
  accA[6] += xv1.z * wv0; accB[6] += xv1.z * wv1; \
  accA[7] += xv1.w * wv0; accB[7] += xv1.w * wv1;

// ---------------- proj: h = relu(x @ Wp + bp) -----------------------------
__global__ __launch_bounds__(256, 3)
void proj_kernel(const float* __restrict__ x,
                 const float* __restrict__ Wp,
                 const float* __restrict__ bp,
                 float* __restrict__ h, int n) {
  __shared__ float x_s[BKP * XT_STRIDE];
  __shared__ float w_s[BKP * HID];
  int t = threadIdx.x;
  int tx = t & 7;
  int ng = t >> 3;
  int n0 = blockIdx.x * 256;

  f4 b0 = ((const f4*)bp)[tx * 2];
  f4 b1 = ((const f4*)bp)[tx * 2 + 1];
  f4 accA[8], accB[8];
  #pragma unroll
  for (int i = 0; i < 8; ++i) { accA[i] = b0; accB[i] = b1; }

  for (int kc = 0; kc < INDIM / BKP; ++kc) {
    #pragma unroll
    for (int i = t; i < 256 * BKP; i += 256) {
      int node = i / BKP, col = i % BKP;
      int gi = n0 + node; if (gi >= n) gi = n - 1;
      x_s[col * XT_STRIDE + node] = x[(size_t)gi * INDIM + kc * BKP + col];
    }
    if (t < BKP * HID / 4)
      ((f4*)w_s)[t] = ((const f4*)(Wp + kc * BKP * HID))[t];
    __syncthreads();
    #pragma unroll
    for (int k = 0; k < BKP; ++k) {
      const float* xr = &x_s[k * XT_STRIDE + ng * 8];
      f4 xv0 = *(const f4*)xr;
      f4 xv1 = *(const f4*)(xr + 4);
      f4 wv0 = *(const f4*)&w_s[k * HID + tx * 8];
      f4 wv1 = *(const f4*)&w_s[k * HID + tx * 8 + 4];
      MT_FMA(xv0, xv1, wv0, wv1)
    }
    __syncthreads();
  }
  #pragma unroll
  for (int i = 0; i < 8; ++i) {
    int node = n0 + ng * 8 + i;
    if (node < n) {
      f4 a = accA[i], b = accB[i];
      RELU4(a) RELU4(b)
      *(f4*)&h[(size_t)node * HID + tx * 8] = a;
      *(f4*)&h[(size_t)node * HID + tx * 8 + 4] = b;
    }
  }
}

// ---------------- degree histogram (sharded + NT edge reads) --------------
__global__ void degree_kernel(const int* __restrict__ dst, int* __restrict__ counts, int e) {
  int r = blockIdx.x & (NR - 1);
  int chunk = blockIdx.x / NR;
  int lo = r * RSIZE, hi = lo + RSIZE;
  int base = chunk * CHUNK_E;
  int end = min(base + CHUNK_E, e);
  for (int i = base + (int)threadIdx.x; i < end; i += 256) {
    int d = __builtin_nontemporal_load(&dst[i]);
    if (d >= lo && d < hi) atomicAdd(&counts[d], 1);
  }
}

// ---------------- scan ----------------------------------------------------
__global__ void scan1_kernel(const int* __restrict__ counts, int* __restrict__ row_ptr,
                             int* __restrict__ bsums, int n) {
  __shared__ int lds[SCAN_T];
  int b = blockIdx.x, t = threadIdx.x;
  int base = b * SCAN_CHUNK + t * SCAN_I;
  int v[SCAN_I];
  int s = 0;
  #pragma unroll
  for (int i = 0; i < SCAN_I; ++i) {
    int idx = base + i;
    v[i] = (idx < n) ? counts[idx] : 0;
    s += v[i];
  }
  lds[t] = s;
  __syncthreads();
  for (int off = 1; off < SCAN_T; off <<= 1) {
    int y = (t >= off) ? lds[t - off] : 0;
    __syncthreads();
    lds[t] += y;
    __syncthreads();
  }
  int incl = lds[t];
  int run = incl - s;
  #pragma unroll
  for (int i = 0; i < SCAN_I; ++i) {
    int idx = base + i;
    if (idx < n) row_ptr[idx] = run;
    run += v[i];
  }
  if (t == SCAN_T - 1) bsums[b] = incl;
}

__global__ void scan2_kernel(int* __restrict__ bsums, int nb) {
  __shared__ int lds[SCAN_T];
  int t = threadIdx.x;
  int v = (t < nb) ? bsums[t] : 0;
  lds[t] = v;
  __syncthreads();
  for (int off = 1; off < SCAN_T; off <<= 1) {
    int y = (t >= off) ? lds[t - off] : 0;
    __syncthreads();
    lds[t] += y;
    __syncthreads();
  }
  if (t < nb) bsums[t] = lds[t] - v;
}

__global__ void scan3_kernel(int* __restrict__ row_ptr, const int* __restrict__ bsums,
                             int* __restrict__ cursor, int n, int e) {
  int i = blockIdx.x * blockDim.x + threadIdx.x;
  if (i < n) {
    int v = row_ptr[i] + bsums[i / SCAN_CHUNK];
    row_ptr[i] = v;
    cursor[i] = v;
  }
  if (i == n) row_ptr[n] = e;
}

// ---------------- scatter into CSR (sharded + NT edge reads) --------------
__global__ void scatter_kernel(const int* __restrict__ src, const int* __restrict__ dst,
                               int* __restrict__ cursor, int* __restrict__ csr_src, int e) {
  int r = blockIdx.x & (NR - 1);
  int chunk = blockIdx.x / NR;
  int lo = r * RSIZE, hi = lo + RSIZE;
  int base = chunk * CHUNK_E;
  int end = min(base + CHUNK_E, e);
  for (int i = base + (int)threadIdx.x; i < end; i += 256) {
    int d = __builtin_nontemporal_load(&dst[i]);
    if (d >= lo && d < hi) {
      int s = __builtin_nontemporal_load(&src[i]);
      int pos = atomicAdd(&cursor[d], 1);
      csr_src[pos] = s;
    }
  }
}

// ---------------- mean aggregation (pull, CSR) ----------------------------
__global__ void aggr_kernel(const float* __restrict__ hin,
                            const int* __restrict__ row_ptr,
                            const int* __restrict__ csr_src,
                            float* __restrict__ aggr, int n) {
  int lane = threadIdx.x & 63;
  int grp = lane >> 4, sub = lane & 15;
  int node = (blockIdx.x * blockDim.x + threadIdx.x) >> 6;
  if (node >= n) return;
  int r0 = row_ptr[node], r1 = row_ptr[node + 1];
  f4 acc0 = {0.f, 0.f, 0.f, 0.f}, acc1 = {0.f, 0.f, 0.f, 0.f};
  int p = r0;
  for (; p + 8 <= r1; p += 8) {
    int i0 = csr_src[p + grp];
    int i1 = csr_src[p + 4 + grp];
    f4 v0 = *((const f4*)(hin + (size_t)i0 * HID) + sub);
    f4 v1 = *((const f4*)(hin + (size_t)i1 * HID) + sub);
    acc0 += v0;
    acc1 += v1;
  }
  if (p + 4 <= r1) {
    int i0 = csr_src[p + grp];
    acc0 += *((const f4*)(hin + (size_t)i0 * HID) + sub);
    p += 4;
  }
  int rem = r1 - p;
  if (grp < rem) {
    int i0 = csr_src[p + grp];
    acc1 += *((const f4*)(hin + (size_t)i0 * HID) + sub);
  }
  acc0 += acc1;
  #pragma unroll
  for (int c = 0; c < 4; ++c) {
    float v = acc0[c];
    v += __shfl_xor(v, 16, 64);
    v += __shfl_xor(v, 32, 64);
    acc0[c] = v;
  }
  int deg = r1 - r0;
  float rdeg = 1.f / (float)(deg > 1 ? deg : 1);
  if (grp == 0) {
    f4 o = acc0 * rdeg;
    *((f4*)(aggr + (size_t)node * HID) + sub) = o;
  }
}

// ---------------- gemm: hout = relu(aggr@Wl + bl + hin@Wr) ---------------
#define GEMM_BODY(aggrp, hinp) \
  for (int kc = 0; kc < HID / BKG; ++kc) { \
    _Pragma("unroll") \
    for (int i = t; i < 256 * BKG; i += 256) { \
      int node = i >> 4, k = i & 15; \
      int gi = n0 + node; if (gi >= n) gi = n - 1; \
      a_s[k * XT_STRIDE + node] = aggrp[(size_t)gi * HID + kc * BKG + k]; \
      h_s[k * XT_STRIDE + node] = hinp[(size_t)gi * HID + kc * BKG + k]; \
    } \
    if (t < BKG * HID / 4) { \
      ((f4*)wl_s)[t] = ((const f4*)(Wl + kc * BKG * HID))[t]; \
      ((f4*)wr_s)[t] = ((const f4*)(Wr + kc * BKG * HID))[t]; \
    } \
    __syncthreads(); \
    _Pragma("unroll") \
    for (int k = 0; k < BKG; ++k) { \
      const float* ar = &a_s[k * XT_STRIDE + ng * 8]; \
      const float* hr = &h_s[k * XT_STRIDE + ng * 8]; \
      f4 av0 = *(const f4*)ar; \
      f4 av1 = *(const f4*)(ar + 4); \
      f4 hv0 = *(const f4*)hr; \
      f4 hv1 = *(const f4*)(hr + 4); \
      f4 wl0 = *(const f4*)&wl_s[k * HID + tx * 8]; \
      f4 wl1 = *(const f4*)&wl_s[k * HID + tx * 8 + 4]; \
      f4 wr0 = *(const f4*)&wr_s[k * HID + tx * 8]; \
      f4 wr1 = *(const f4*)&wr_s[k * HID + tx * 8 + 4]; \
      accA[0] += av0.x * wl0 + hv0.x * wr0;  accB[0] += av0.x * wl1 + hv0.x * wr1; \
      accA[1] += av0.y * wl0 + hv0.y * wr0;  accB[1] += av0.y * wl1 + hv0.y * wr1; \
      accA[2] += av0.z * wl0 + hv0.z * wr0;  accB[2] += av0.z * wl1 + hv0.z * wr1; \
      accA[3] += av0.w * wl0 + hv0.w * wr0;  accB[3] += av0.w * wl1 + hv0.w * wr1; \
      accA[4] += av1.x * wl0 + hv1.x * wr0;  accB[4] += av1.x * wl1 + hv1.x * wr1; \
      accA[5] += av1.y * wl0 + hv1.y * wr0;  accB[5] += av1.y * wl1 + hv1.y * wr1; \
      accA[6] += av1.z * wl0 + hv1.z * wr0;  accB[6] += av1.z * wl1 + hv1.z * wr1; \
      accA[7] += av1.w * wl0 + hv1.w * wr0;  accB[7] += av1.w * wl1 + hv1.w * wr1; \
    } \
    __syncthreads(); \
  }

__global__ __launch_bounds__(256, 3)
void gemm_kernel(const float* __restrict__ aggr,
                 const float* hin,
                 const float* __restrict__ Wl, const float* __restrict__ bl,
                 const float* __restrict__ Wr,
                 float* hout, int n) {
  __shared__ float a_s[BKG * XT_STRIDE];
  __shared__ float h_s[BKG * XT_STRIDE];
  __shared__ float wl_s[BKG * HID];
  __shared__ float wr_s[BKG * HID];
  int t = threadIdx.x;
  int tx = t & 7;
  int ng = t >> 3;
  int n0 = blockIdx.x * 256;

  f4 b0 = ((const f4*)bl)[tx * 2];
  f4 b1 = ((const f4*)bl)[tx * 2 + 1];
  f4 accA[8], accB[8];
  #pragma unroll
  for (int i = 0; i < 8; ++i) { accA[i] = b0; accB[i] = b1; }

  GEMM_BODY(aggr, hin)

  #pragma unroll
  for (int i = 0; i < 8; ++i) {
    int node = n0 + ng * 8 + i;
    if (node < n) {
      f4 a = accA[i], b = accB[i];
      RELU4(a) RELU4(b)
      *(f4*)&hout[(size_t)node * HID + tx * 8] = a;
      *(f4*)&hout[(size_t)node * HID + tx * 8 + 4] = b;
    }
  }
}

// ---------------- gemm2 + cls fused ---------------------------------------
__global__ __launch_bounds__(256, 3)
void gemm_cls_kernel(const float* __restrict__ aggr,
                     const float* __restrict__ hin,
                     const float* __restrict__ Wl, const float* __restrict__ bl,
                     const float* __restrict__ Wr,
                     const float* __restrict__ Wc, const float* __restrict__ bc,
                     float* __restrict__ out, int n) {
  __shared__ float a_s[BKG * XT_STRIDE];
  __shared__ float h_s[BKG * XT_STRIDE];
  __shared__ float wl_s[BKG * HID];
  __shared__ float wr_s[BKG * HID];
  int t = threadIdx.x;
  int tx = t & 7;
  int ng = t >> 3;
  int n0 = blockIdx.x * 256;

  f4 b0 = ((const f4*)bl)[tx * 2];
  f4 b1 = ((const f4*)bl)[tx * 2 + 1];
  f4 accA[8], accB[8];
  #pragma unroll
  for (int i = 0; i < 8; ++i) { accA[i] = b0; accB[i] = b1; }

  GEMM_BODY(aggr, hin)

  f4 wc0 = ((const f4*)Wc)[tx * 2];
  f4 wc1 = ((const f4*)Wc)[tx * 2 + 1];
  float bcv = bc[0];
  #pragma unroll
  for (int i = 0; i < 8; ++i) {
    f4 a = accA[i], b = accB[i];
    RELU4(a) RELU4(b)
    float s = a.x * wc0.x + a.y * wc0.y + a.z * wc0.z + a.w * wc0.w
            + b.x * wc1.x + b.y * wc1.y + b.z * wc1.z + b.w * wc1.w;
    s += __shfl_xor(s, 1, 64);
    s += __shfl_xor(s, 2, 64);
    s += __shfl_xor(s, 4, 64);
    int node = n0 + ng * 8 + i;
    if (tx == 0 && node < n) out[node] = s + bcv;
  }
}

extern "C" void kernel_launch(void* const* d_in, const int* in_sizes, int n_in,
                              void* d_out, int out_size, void* d_ws, size_t ws_size,
                              hipStream_t stream) {
  const float* x   = (const float*)d_in[0];
  const int*   ei  = (const int*)d_in[1];
  const float* Wp  = (const float*)d_in[2];
  const float* bp  = (const float*)d_in[3];
  const float* W1l = (const float*)d_in[4];
  const float* b1l = (const float*)d_in[5];
  const float* W1r = (const float*)d_in[6];
  const float* W2l = (const float*)d_in[7];
  const float* b2l = (const float*)d_in[8];
  const float* W2r = (const float*)d_in[9];
  const float* Wc  = (const float*)d_in[10];
  const float* bc  = (const float*)d_in[11];
  float* out = (float*)d_out;

  const int N = NNODES, E = NEDGES;
  const int* src = ei;
  const int* dst = ei + E;

  char* ws = (char*)d_ws;
  float* h       = (float*)(ws + 0);
  float* aggr    = (float*)(ws + 51200000);
  int*   counts  = (int*)  (ws + 102400000);
  int*   row_ptr = (int*)  (ws + 103200000);
  int*   cursor  = (int*)  (ws + 104000256);
  int*   csr_src = (int*)  (ws + 104800256);
  int*   bsums   = (int*)  (ws + 117600256);

  hipMemsetAsync(counts, 0, (size_t)N * 4, stream);

  proj_kernel<<<782, 256, 0, stream>>>(x, Wp, bp, h, N);

  int nchunks = (E + CHUNK_E - 1) / CHUNK_E;
  degree_kernel<<<nchunks * NR, 256, 0, stream>>>(dst, counts, E);
  int nb = (N + SCAN_CHUNK - 1) / SCAN_CHUNK;
  scan1_kernel<<<nb, SCAN_T, 0, stream>>>(counts, row_ptr, bsums, N);
  scan2_kernel<<<1, SCAN_T, 0, stream>>>(bsums, nb);
  scan3_kernel<<<(N + 256) / 256, 256, 0, stream>>>(row_ptr, bsums, cursor, N, E);
  scatter_kernel<<<nchunks * NR, 256, 0, stream>>>(src, dst, cursor, csr_src, E);

  aggr_kernel<<<(N + 3) / 4, 256, 0, stream>>>(h, row_ptr, csr_src, aggr, N);
  gemm_kernel<<<782, 256, 0, stream>>>(aggr, h, W1l, b1l, W1r, h, N);

  aggr_kernel<<<(N + 3) / 4, 256, 0, stream>>>(h, row_ptr, csr_src, aggr, N);
  gemm_cls_kernel<<<782, 256, 0, stream>>>(aggr, h, W2l, b2l, W2r, Wc, bc, out, N);
}